// Round 4
// baseline (2429.772 us; speedup 1.0000x reference)
//
#include <hip/hip_runtime.h>
#include <hip/hip_bf16.h>

#define NHD 16
#define HSD 64
#define KVLD 128
#define QLD 128
#define CD 1024
#define BD 2
#define TD 2048

// ---------- small precompute GEMMs (fp32 inputs, L2-resident) ----------

// M1[i][j] = sum_c W_uq[c][i] * W_uk[c][j]   (i,j < 128)
__global__ __launch_bounds__(256) void k_m1(const float* __restrict__ wuq,
                                            const float* __restrict__ wuk,
                                            float* __restrict__ m1) {
    int idx = blockIdx.x * 256 + threadIdx.x;  // i*128 + j
    int i = idx >> 7, j = idx & 127;
    float acc = 0.f;
    for (int c = 0; c < CD; ++c)
        acc += wuq[c * QLD + i] * wuk[c * KVLD + j];
    m1[idx] = acc;
}

// keff[c][j] = sum_i W_dq[i][c] * M1[i][j]   (c < 1024, j < 128)
__global__ __launch_bounds__(256) void k_keff(const float* __restrict__ wdq,
                                              const float* __restrict__ m1,
                                              float* __restrict__ keff) {
    int idx = blockIdx.x * 256 + threadIdx.x;  // c*128 + j
    int c = idx >> 7, j = idx & 127;
    float acc = 0.f;
    for (int i = 0; i < QLD; ++i)
        acc += wdq[i * CD + c] * m1[i * KVLD + j];
    keff[idx] = acc;
}

// veff[h][l][d] = sum_c0 W_uv[c0][l] * W_o[h*64+d][c0]
__global__ __launch_bounds__(256) void k_veff(const float* __restrict__ wuv,
                                              const float* __restrict__ wo,
                                              float* __restrict__ veff) {
    int idx = blockIdx.x * 256 + threadIdx.x;  // ((h*128+l)*64+d)
    int d = idx & 63;
    int l = (idx >> 6) & 127;
    int h = idx >> 13;
    int cc = h * HSD + d;
    float acc = 0.f;
    for (int c0 = 0; c0 < CD; ++c0)
        acc += wuv[c0 * KVLD + l] * wo[cc * CD + c0];
    veff[idx] = acc;
}

// E[h][i][l] = (1/8) * sum_d W_uq[(h*64+d)][i] * keff[(h*64+d)][l]
// (per-head effective query transform; 1/sqrt(HS) folded in)
__global__ __launch_bounds__(256) void k_E(const float* __restrict__ wuq,
                                           const float* __restrict__ keff,
                                           float* __restrict__ E) {
    int idx = blockIdx.x * 256 + threadIdx.x;  // ((h*128+i)*128+l)
    int l = idx & 127;
    int i = (idx >> 7) & 127;
    int h = idx >> 14;
    float acc = 0.f;
    for (int d = 0; d < HSD; ++d)
        acc += wuq[(h * HSD + d) * QLD + i] * keff[(h * HSD + d) * KVLD + l];
    E[idx] = 0.125f * acc;
}

// ckv[t][l] = sum_c x[t][c] * W_dkv[l][c]; fp32 copy to output 1
__global__ __launch_bounds__(256) void k_ckv(const float* __restrict__ x,
                                             const float* __restrict__ wdkv,
                                             float* __restrict__ ckv,
                                             float* __restrict__ ckv_out) {
    int idx = blockIdx.x * 256 + threadIdx.x;  // t*128 + l
    int t = idx >> 7, l = idx & 127;
    float acc = 0.f;
    for (int c = 0; c < CD; ++c)
        acc += x[t * CD + c] * wdkv[l * CD + c];
    ckv[idx] = acc;
    ckv_out[idx] = acc;
}

// Q1[t][i] = sum_c x[t][c] * W_dq[i][c]
__global__ __launch_bounds__(256) void k_q1(const float* __restrict__ x,
                                            const float* __restrict__ wdq,
                                            float* __restrict__ q1) {
    int idx = blockIdx.x * 256 + threadIdx.x;  // t*128 + i
    int t = idx >> 7, i = idx & 127;
    float acc = 0.f;
    for (int c = 0; c < CD; ++c)
        acc += x[t * CD + c] * wdq[i * CD + c];
    q1[idx] = acc;
}

// Flash attention: one block = (b, h, 32 query rows). 256 threads:
// thread = (row r = tid>>3, col-group cg = tid&7).
// LDS strides padded for bank-conflict freedom: 132 / 65 / 68.
// ql tile computed on the fly: ql = Q1_tile @ E[h].
__global__ __launch_bounds__(256) void k_flash(const float* __restrict__ Q1,
                                               const float* __restrict__ E,
                                               const float* __restrict__ ckv,
                                               const float* __restrict__ veff,
                                               float* __restrict__ yout) {
    const int qt = blockIdx.x;   // 0..63
    const int h = blockIdx.y;    // 0..15
    const int b = blockIdx.z;    // 0..1
    const int tid = threadIdx.x;
    const int r = tid >> 3;      // 0..31
    const int cg = tid & 7;      // 0..7
    const int row0 = qt * 32;
    const int tg = row0 + r;

    __shared__ float qlS[32 * 132];
    __shared__ float kvS[128 * 68];  // >= 64*132; reused as v_eff[128*68] in epilogue
    __shared__ float pS[32 * 65];
    __shared__ float q1S[32 * 132];

    // stage Q1 tile (32x128)
    const float* q1base = Q1 + (size_t)(b * TD + row0) * QLD;
    for (int i = tid; i < 32 * 32; i += 256) {
        int rr = i >> 5, c4 = (i & 31) << 2;
        *(float4*)&q1S[rr * 132 + c4] = *(const float4*)(q1base + rr * QLD + c4);
    }
    __syncthreads();

    // qlS[r][cg*16+j] = sum_i q1S[r][i] * E[h][i][cg*16+j]
    {
        const float* Eh = E + (size_t)h * QLD * KVLD + cg * 16;
        float a[16];
#pragma unroll
        for (int j = 0; j < 16; ++j) a[j] = 0.f;
        for (int i = 0; i < 128; ++i) {
            float qi = q1S[r * 132 + i];
            const float* er = Eh + i * KVLD;
            float4 e0 = *(const float4*)(er + 0);
            float4 e1 = *(const float4*)(er + 4);
            float4 e2 = *(const float4*)(er + 8);
            float4 e3 = *(const float4*)(er + 12);
            a[0] += qi * e0.x;  a[1] += qi * e0.y;  a[2] += qi * e0.z;  a[3] += qi * e0.w;
            a[4] += qi * e1.x;  a[5] += qi * e1.y;  a[6] += qi * e1.z;  a[7] += qi * e1.w;
            a[8] += qi * e2.x;  a[9] += qi * e2.y;  a[10] += qi * e2.z; a[11] += qi * e2.w;
            a[12] += qi * e3.x; a[13] += qi * e3.y; a[14] += qi * e3.z; a[15] += qi * e3.w;
        }
#pragma unroll
        for (int j = 0; j < 16; ++j) qlS[r * 132 + cg * 16 + j] = a[j];
    }

    float ctx[16];
#pragma unroll
    for (int j = 0; j < 16; ++j) ctx[j] = 0.f;
    float m_run = -INFINITY, l_run = 0.f;

    const int nt = (row0 + 31) / 64 + 1;
    const float* ckb = ckv + (size_t)b * TD * KVLD;

    for (int tile = 0; tile < nt; ++tile) {
        const int s0 = tile * 64;
        __syncthreads();  // fences qlS writes (tile 0) and previous tile's kvS readers
        for (int i = tid; i < 64 * 32; i += 256) {
            int sl = i >> 5, c4 = (i & 31) << 2;
            *(float4*)&kvS[sl * 132 + c4] = *(const float4*)(ckb + (size_t)(s0 + sl) * KVLD + c4);
        }
        __syncthreads();

        // scores: thread handles s = s0 + k*8 + cg, k=0..7 (scale already in E)
        float acc[8];
#pragma unroll
        for (int k = 0; k < 8; ++k) acc[k] = 0.f;
        for (int c4 = 0; c4 < 128; c4 += 4) {
            float4 q4 = *(const float4*)&qlS[r * 132 + c4];
#pragma unroll
            for (int k = 0; k < 8; ++k) {
                float4 k4 = *(const float4*)&kvS[(k * 8 + cg) * 132 + c4];
                acc[k] += q4.x * k4.x + q4.y * k4.y + q4.z * k4.z + q4.w * k4.w;
            }
        }
        float mt = -INFINITY;
#pragma unroll
        for (int k = 0; k < 8; ++k) {
            int sg = s0 + k * 8 + cg;
            acc[k] = (sg <= tg) ? acc[k] : -INFINITY;
            mt = fmaxf(mt, acc[k]);
        }
#pragma unroll
        for (int off = 1; off < 8; off <<= 1)
            mt = fmaxf(mt, __shfl_xor(mt, off));
        float m_new = fmaxf(m_run, mt);            // finite from tile 0 on (s=0 unmasked)
        float alpha = __expf(m_run - m_new);       // exp(-inf)=0 at first tile
        float psum = 0.f;
#pragma unroll
        for (int k = 0; k < 8; ++k) {
            float p = __expf(acc[k] - m_new);      // masked -> 0
            pS[r * 65 + k * 8 + cg] = p;
            psum += p;
        }
#pragma unroll
        for (int off = 1; off < 8; off <<= 1)
            psum += __shfl_xor(psum, off);
        l_run = alpha * l_run + psum;
        m_run = m_new;
#pragma unroll
        for (int j = 0; j < 16; ++j) ctx[j] *= alpha;

        __builtin_amdgcn_wave_barrier();  // pS row r produced/consumed within one wave

        // ctx += P @ kv
        for (int s = 0; s < 64; ++s) {
            float p = pS[r * 65 + s];
            const float* kr = &kvS[s * 132 + cg * 16];
            float4 a0 = *(const float4*)(kr + 0);
            float4 a1 = *(const float4*)(kr + 4);
            float4 a2 = *(const float4*)(kr + 8);
            float4 a3 = *(const float4*)(kr + 12);
            ctx[0] += p * a0.x;  ctx[1] += p * a0.y;  ctx[2] += p * a0.z;  ctx[3] += p * a0.w;
            ctx[4] += p * a1.x;  ctx[5] += p * a1.y;  ctx[6] += p * a1.z;  ctx[7] += p * a1.w;
            ctx[8] += p * a2.x;  ctx[9] += p * a2.y;  ctx[10] += p * a2.z; ctx[11] += p * a2.w;
            ctx[12] += p * a3.x; ctx[13] += p * a3.y; ctx[14] += p * a3.z; ctx[15] += p * a3.w;
        }
    }

    // normalize, then y = ctx @ veff[h]
    float inv_l = 1.f / l_run;
#pragma unroll
    for (int j = 0; j < 16; ++j) ctx[j] *= inv_l;
    __syncthreads();  // all waves done with main-loop qlS/kvS reads
#pragma unroll
    for (int j = 0; j < 16; ++j) qlS[r * 132 + cg * 16 + j] = ctx[j];
    const float* vb = veff + (size_t)h * KVLD * HSD;
    for (int i = tid; i < 128 * 16; i += 256) {
        int l = i >> 4, d4 = (i & 15) << 2;
        *(float4*)&kvS[l * 68 + d4] = *(const float4*)(vb + l * HSD + d4);
    }
    __syncthreads();

    float ya[8];
#pragma unroll
    for (int k = 0; k < 8; ++k) ya[k] = 0.f;
    for (int l = 0; l < 128; ++l) {
        float cv = qlS[r * 132 + l];
        float4 v0 = *(const float4*)&kvS[l * 68 + cg * 8];
        float4 v1 = *(const float4*)&kvS[l * 68 + cg * 8 + 4];
        ya[0] += cv * v0.x; ya[1] += cv * v0.y; ya[2] += cv * v0.z; ya[3] += cv * v0.w;
        ya[4] += cv * v1.x; ya[5] += cv * v1.y; ya[6] += cv * v1.z; ya[7] += cv * v1.w;
    }
    float* yo = yout + ((size_t)(b * TD + tg)) * CD + h * HSD + cg * 8;
#pragma unroll
    for (int k = 0; k < 8; ++k) yo[k] = ya[k];
}

extern "C" void kernel_launch(void* const* d_in, const int* in_sizes, int n_in,
                              void* d_out, int out_size, void* d_ws, size_t ws_size,
                              hipStream_t stream) {
    const float* x    = (const float*)d_in[0];
    const float* wdq  = (const float*)d_in[1];
    const float* wuq  = (const float*)d_in[2];
    const float* wdkv = (const float*)d_in[3];
    const float* wuk  = (const float*)d_in[4];
    const float* wuv  = (const float*)d_in[5];
    const float* wo   = (const float*)d_in[6];
    float* yout = (float*)d_out;                       // (B,T,C) fp32
    float* ckv_out = yout + (size_t)BD * TD * CD;      // (B,T,KVL) fp32

    // ws usage: 1,589,248 floats = 6.36 MB
    float* ws = (float*)d_ws;
    float* M1   = ws;               // 16384
    float* keff = M1 + 16384;       // 131072
    float* veff = keff + 131072;    // 131072
    float* E    = veff + 131072;    // 262144
    float* Q1   = E + 262144;       // 524288
    float* ckv  = Q1 + 524288;      // 524288

    k_m1  <<<64,   256, 0, stream>>>(wuq, wuk, M1);
    k_keff<<<512,  256, 0, stream>>>(wdq, M1, keff);
    k_veff<<<512,  256, 0, stream>>>(wuv, wo, veff);
    k_E   <<<1024, 256, 0, stream>>>(wuq, keff, E);
    k_ckv <<<2048, 256, 0, stream>>>(x, wdkv, ckv, ckv_out);
    k_q1  <<<2048, 256, 0, stream>>>(x, wdq, Q1);

    dim3 grid(64, 16, 2);
    k_flash<<<grid, 256, 0, stream>>>(Q1, E, ckv, veff, yout);
}

// Round 5
// 971.912 us; speedup vs baseline: 2.5000x; 2.5000x over previous
//
#include <hip/hip_runtime.h>
#include <hip/hip_bf16.h>

typedef __hip_bfloat16 bf16;
typedef __attribute__((ext_vector_type(8))) short short8;
typedef __attribute__((ext_vector_type(4))) float f32x4;

#define NHD 16
#define HSD 64
#define KVLD 128
#define QLD 128
#define CD 1024
#define BD 2
#define TD 2048

__device__ __forceinline__ short8 ld8(const bf16* p) { return *(const short8*)p; }
__device__ __forceinline__ void st8(bf16* p, short8 v) { *(short8*)p = v; }

// ---------- small precompute GEMMs ----------

// M1[i][j] = sum_c W_uq[c][i] * W_uk[c][j]
__global__ __launch_bounds__(256) void k_m1(const float* __restrict__ wuq,
                                            const float* __restrict__ wuk,
                                            float* __restrict__ m1) {
    int idx = blockIdx.x * 256 + threadIdx.x;
    int i = idx >> 7, j = idx & 127;
    float acc = 0.f;
    for (int c = 0; c < CD; ++c)
        acc += wuq[c * QLD + i] * wuk[c * KVLD + j];
    m1[idx] = acc;
}

// keff[c][j] = sum_i W_dq[i][c] * M1[i][j]
__global__ __launch_bounds__(256) void k_keff(const float* __restrict__ wdq,
                                              const float* __restrict__ m1,
                                              float* __restrict__ keff) {
    int idx = blockIdx.x * 256 + threadIdx.x;
    int c = idx >> 7, j = idx & 127;
    float acc = 0.f;
    for (int i = 0; i < QLD; ++i)
        acc += wdq[i * CD + c] * m1[i * KVLD + j];
    keff[idx] = acc;
}

// veffT_bf[h][d][l] = bf16( sum_c0 W_uv[c0][l] * W_o[(h*64+d)][c0] )
__global__ __launch_bounds__(256) void k_veff(const float* __restrict__ wuv,
                                              const float* __restrict__ wo,
                                              bf16* __restrict__ veffT_bf) {
    int idx = blockIdx.x * 256 + threadIdx.x;  // ((h*128+l)*64+d)
    int d = idx & 63;
    int l = (idx >> 6) & 127;
    int h = idx >> 13;
    int cc = h * HSD + d;
    float acc = 0.f;
    for (int c0 = 0; c0 < CD; ++c0)
        acc += wuv[c0 * KVLD + l] * wo[cc * CD + c0];
    veffT_bf[h * (HSD * KVLD) + d * KVLD + l] = __float2bfloat16(acc);
}

// Et_bf[h][l][i] = bf16( 0.125 * sum_d W_uq[(h*64+d)][i] * keff[(h*64+d)][l] )
__global__ __launch_bounds__(256) void k_E(const float* __restrict__ wuq,
                                           const float* __restrict__ keff,
                                           bf16* __restrict__ Et_bf) {
    int idx = blockIdx.x * 256 + threadIdx.x;  // ((h*128+i)*128+l)
    int l = idx & 127;
    int i = (idx >> 7) & 127;
    int h = idx >> 14;
    float acc = 0.f;
    for (int d = 0; d < HSD; ++d)
        acc += wuq[(h * HSD + d) * QLD + i] * keff[(h * HSD + d) * KVLD + l];
    Et_bf[h * (QLD * KVLD) + l * QLD + i] = __float2bfloat16(0.125f * acc);
}

// ckv: fp32 to d_out; bf16 row-major + bf16 transposed to ws
__global__ __launch_bounds__(256) void k_ckv(const float* __restrict__ x,
                                             const float* __restrict__ wdkv,
                                             float* __restrict__ ckv_out,
                                             bf16* __restrict__ ckv_bf,
                                             bf16* __restrict__ ckvT_bf) {
    int idx = blockIdx.x * 256 + threadIdx.x;  // t*128 + l
    int t = idx >> 7, l = idx & 127;
    float acc = 0.f;
    for (int c = 0; c < CD; ++c)
        acc += x[t * CD + c] * wdkv[l * CD + c];
    ckv_out[idx] = acc;
    bf16 hv = __float2bfloat16(acc);
    ckv_bf[idx] = hv;
    int b = t >> 11, tl = t & 2047;
    ckvT_bf[((size_t)b * KVLD + l) * TD + tl] = hv;
}

// Q1_bf[t][i] = bf16( sum_c x[t][c] * W_dq[i][c] )
__global__ __launch_bounds__(256) void k_q1(const float* __restrict__ x,
                                            const float* __restrict__ wdq,
                                            bf16* __restrict__ q1_bf) {
    int idx = blockIdx.x * 256 + threadIdx.x;  // t*128 + i
    int t = idx >> 7, i = idx & 127;
    float acc = 0.f;
    for (int c = 0; c < CD; ++c)
        acc += x[t * CD + c] * wdq[i * CD + c];
    q1_bf[idx] = __float2bfloat16(acc);
}

// ---------- MFMA flash attention ----------
// Block = (qt, h, b): 64 q-rows, 4 waves x 16 rows. KV tiles of 64.
// LDS (short units): [0, 8704) Q1t/qlS/kvN/ctxS (stride 136)
//                    [8704, 17920) Et(part)/kvT (stride 72)/vT (stride 136)
//                    [17920, 22528) pS per-wave 16x72
// Prologue needs Q1t(8704) + Et(17408) = 26112 shorts total = 52224 B.
__global__ __launch_bounds__(256) void k_flash_mfma(const bf16* __restrict__ Q1_bf,
                                                    const bf16* __restrict__ Et_bf,
                                                    const bf16* __restrict__ ckv_bf,
                                                    const bf16* __restrict__ ckvT_bf,
                                                    const bf16* __restrict__ veffT_bf,
                                                    float* __restrict__ yout) {
    const int qt = blockIdx.x;   // 0..31
    const int h = blockIdx.y;    // 0..15
    const int b = blockIdx.z;    // 0..1
    const int tid = threadIdx.x;
    const int w = tid >> 6;      // wave 0..3
    const int lane = tid & 63;
    const int m16 = lane & 15;   // C-layout col / A-layout row
    const int g = lane >> 4;     // quad
    const int row0 = qt * 64;

    __shared__ __align__(16) short smem_raw[26112];
    bf16* smem = (bf16*)smem_raw;
    bf16* Q1t = smem;            // 64 x 136
    bf16* Ets = smem + 8704;     // 128 x 136
    bf16* kvN = smem;            // 64 x 136
    bf16* kvT = smem + 8704;     // 128 x 72
    bf16* pS  = smem + 17920 + w * 1152;  // 16 x 72 per wave
    bf16* ctxS = smem;           // 64 x 136 (epilogue)
    bf16* vT   = smem + 8704;    // 64 x 136 (epilogue)

    // ---- prologue: stage Q1 tile + Et, compute ql = Q1 @ E, keep as A-frags ----
    {
        const bf16* q1src = Q1_bf + ((size_t)(b * TD + row0)) * QLD;
#pragma unroll
        for (int k = 0; k < 4; ++k) {
            int v = tid + k * 256;
            int row = v >> 4, cv = (v & 15) << 3;
            st8(Q1t + row * 136 + cv, ld8(q1src + row * QLD + cv));
        }
        const bf16* esrc = Et_bf + (size_t)h * QLD * KVLD;
#pragma unroll
        for (int k = 0; k < 8; ++k) {
            int v = tid + k * 256;
            int row = v >> 4, cv = (v & 15) << 3;
            st8(Ets + row * 136 + cv, ld8(esrc + row * QLD + cv));
        }
    }
    __syncthreads();

    f32x4 qc[8];
#pragma unroll
    for (int nb = 0; nb < 8; ++nb) qc[nb] = (f32x4){0.f, 0.f, 0.f, 0.f};
    {
        short8 aq[4];
#pragma unroll
        for (int kf = 0; kf < 4; ++kf)
            aq[kf] = ld8(Q1t + (w * 16 + m16) * 136 + kf * 32 + g * 8);
#pragma unroll
        for (int nb = 0; nb < 8; ++nb)
#pragma unroll
            for (int kf = 0; kf < 4; ++kf) {
                short8 bq = ld8(Ets + (nb * 16 + m16) * 136 + kf * 32 + g * 8);
                qc[nb] = __builtin_amdgcn_mfma_f32_16x16x32_bf16(aq[kf], bq, qc[nb], 0, 0, 0);
            }
    }
    __syncthreads();  // done reading Q1t/Ets

    // write ql to LDS (row-major, bf16), re-read as A-frags
#pragma unroll
    for (int nb = 0; nb < 8; ++nb)
#pragma unroll
        for (int r = 0; r < 4; ++r)
            Q1t[(w * 16 + g * 4 + r) * 136 + nb * 16 + m16] = __float2bfloat16(qc[nb][r]);
    __syncthreads();

    short8 qlA[4];
#pragma unroll
    for (int kf = 0; kf < 4; ++kf)
        qlA[kf] = ld8(Q1t + (w * 16 + m16) * 136 + kf * 32 + g * 8);

    // ---- main loop ----
    f32x4 cx[8];
#pragma unroll
    for (int nb = 0; nb < 8; ++nb) cx[nb] = (f32x4){0.f, 0.f, 0.f, 0.f};
    float mrow[4] = {-INFINITY, -INFINITY, -INFINITY, -INFINITY};
    float lrow[4] = {0.f, 0.f, 0.f, 0.f};

    const bf16* ckb = ckv_bf + (size_t)b * TD * KVLD;
    const bf16* ckTb = ckvT_bf + (size_t)b * KVLD * TD;
    const int nt = qt + 1;

    for (int tile = 0; tile < nt; ++tile) {
        const int s0 = tile * 64;
        const bool diag = (tile == qt);
        __syncthreads();  // previous tile's PV / prologue A-frag reads done

        // stage kvN (64x128, stride 136) and kvT (128x64, stride 72)
#pragma unroll
        for (int k = 0; k < 4; ++k) {
            int v = tid + k * 256;
            int row = v >> 4, cv = (v & 15) << 3;
            st8(kvN + row * 136 + cv, ld8(ckb + (size_t)(s0 + row) * KVLD + cv));
        }
#pragma unroll
        for (int k = 0; k < 4; ++k) {
            int v = tid + k * 256;
            int row = v >> 3, cv = (v & 7) << 3;
            st8(kvT + row * 72 + cv, ld8(ckTb + (size_t)row * TD + s0 + cv));
        }
        __syncthreads();

        // S = ql @ kv^T  (16x64 per wave)
        f32x4 sa[4];
#pragma unroll
        for (int nb = 0; nb < 4; ++nb) sa[nb] = (f32x4){0.f, 0.f, 0.f, 0.f};
#pragma unroll
        for (int nb = 0; nb < 4; ++nb)
#pragma unroll
            for (int kf = 0; kf < 4; ++kf) {
                short8 bk = ld8(kvN + (nb * 16 + m16) * 136 + kf * 32 + g * 8);
                sa[nb] = __builtin_amdgcn_mfma_f32_16x16x32_bf16(qlA[kf], bk, sa[nb], 0, 0, 0);
            }

        // online softmax (rows = w*16 + g*4 + r)
        if (diag) {
#pragma unroll
            for (int nb = 0; nb < 4; ++nb)
#pragma unroll
                for (int r = 0; r < 4; ++r) {
                    int sg = s0 + nb * 16 + m16;
                    int rg = row0 + w * 16 + g * 4 + r;
                    if (sg > rg) sa[nb][r] = -INFINITY;
                }
        }
        float mt[4], al[4], ps[4];
#pragma unroll
        for (int r = 0; r < 4; ++r) {
            float v = fmaxf(fmaxf(sa[0][r], sa[1][r]), fmaxf(sa[2][r], sa[3][r]));
#pragma unroll
            for (int off = 1; off < 16; off <<= 1)
                v = fmaxf(v, __shfl_xor(v, off));
            mt[r] = fmaxf(mrow[r], v);
            al[r] = __expf(mrow[r] - mt[r]);
            mrow[r] = mt[r];
        }
        float pv[4][4];
#pragma unroll
        for (int nb = 0; nb < 4; ++nb)
#pragma unroll
            for (int r = 0; r < 4; ++r)
                pv[nb][r] = __expf(sa[nb][r] - mt[r]);
#pragma unroll
        for (int r = 0; r < 4; ++r) {
            float v = pv[0][r] + pv[1][r] + pv[2][r] + pv[3][r];
#pragma unroll
            for (int off = 1; off < 16; off <<= 1)
                v += __shfl_xor(v, off);
            ps[r] = v;
            lrow[r] = al[r] * lrow[r] + ps[r];
        }
#pragma unroll
        for (int nb = 0; nb < 8; ++nb)
#pragma unroll
            for (int r = 0; r < 4; ++r)
                cx[nb][r] *= al[r];
        // write P (bf16) to per-wave LDS strip
#pragma unroll
        for (int nb = 0; nb < 4; ++nb)
#pragma unroll
            for (int r = 0; r < 4; ++r)
                pS[(g * 4 + r) * 72 + nb * 16 + m16] = __float2bfloat16(pv[nb][r]);
        __syncthreads();  // pS + kvT stable for PV

        // ctx += P @ kv  (16x128 per wave)
        short8 pA[2];
#pragma unroll
        for (int kf = 0; kf < 2; ++kf)
            pA[kf] = ld8(pS + m16 * 72 + kf * 32 + g * 8);
#pragma unroll
        for (int nb = 0; nb < 8; ++nb)
#pragma unroll
            for (int kf = 0; kf < 2; ++kf) {
                short8 bv = ld8(kvT + (nb * 16 + m16) * 72 + kf * 32 + g * 8);
                cx[nb] = __builtin_amdgcn_mfma_f32_16x16x32_bf16(pA[kf], bv, cx[nb], 0, 0, 0);
            }
    }

    // ---- epilogue: y = (ctx / l) @ veff ----
    float invl[4];
#pragma unroll
    for (int r = 0; r < 4; ++r) invl[r] = 1.f / lrow[r];
#pragma unroll
    for (int nb = 0; nb < 8; ++nb)
#pragma unroll
        for (int r = 0; r < 4; ++r)
            cx[nb][r] *= invl[r];
    __syncthreads();  // all waves done with kvN/kvT before reuse
#pragma unroll
    for (int nb = 0; nb < 8; ++nb)
#pragma unroll
        for (int r = 0; r < 4; ++r)
            ctxS[(w * 16 + g * 4 + r) * 136 + nb * 16 + m16] = __float2bfloat16(cx[nb][r]);
    {
        const bf16* vsrc = veffT_bf + (size_t)h * HSD * KVLD;
#pragma unroll
        for (int k = 0; k < 4; ++k) {
            int v = tid + k * 256;
            int row = v >> 4, cv = (v & 15) << 3;
            st8(vT + row * 136 + cv, ld8(vsrc + row * KVLD + cv));
        }
    }
    __syncthreads();

    f32x4 ya[4];
#pragma unroll
    for (int nb = 0; nb < 4; ++nb) ya[nb] = (f32x4){0.f, 0.f, 0.f, 0.f};
    short8 ca[4];
#pragma unroll
    for (int kf = 0; kf < 4; ++kf)
        ca[kf] = ld8(ctxS + (w * 16 + m16) * 136 + kf * 32 + g * 8);
#pragma unroll
    for (int nb = 0; nb < 4; ++nb)
#pragma unroll
        for (int kf = 0; kf < 4; ++kf) {
            short8 bv = ld8(vT + (nb * 16 + m16) * 136 + kf * 32 + g * 8);
            ya[nb] = __builtin_amdgcn_mfma_f32_16x16x32_bf16(ca[kf], bv, ya[nb], 0, 0, 0);
        }
#pragma unroll
    for (int nb = 0; nb < 4; ++nb)
#pragma unroll
        for (int r = 0; r < 4; ++r) {
            int rg = row0 + w * 16 + g * 4 + r;
            yout[((size_t)b * TD + rg) * CD + h * HSD + nb * 16 + m16] = ya[nb][r];
        }
}

extern "C" void kernel_launch(void* const* d_in, const int* in_sizes, int n_in,
                              void* d_out, int out_size, void* d_ws, size_t ws_size,
                              hipStream_t stream) {
    const float* x    = (const float*)d_in[0];
    const float* wdq  = (const float*)d_in[1];
    const float* wuq  = (const float*)d_in[2];
    const float* wdkv = (const float*)d_in[3];
    const float* wuk  = (const float*)d_in[4];
    const float* wuv  = (const float*)d_in[5];
    const float* wo   = (const float*)d_in[6];
    float* yout = (float*)d_out;                   // (B,T,C) fp32
    float* ckv_out = yout + (size_t)BD * TD * CD;  // (B,T,KVL) fp32

    // ws: 589824 B fp32 + 3932160 B bf16 = 4.52 MB (<6.36 MB proven OK)
    float* ws = (float*)d_ws;
    float* M1   = ws;                                   // 16384 f
    float* keff = M1 + 16384;                           // 131072 f
    bf16* Et_bf    = (bf16*)(keff + 131072);            // 262144 bf16 [h][l][i]
    bf16* veffT_bf = Et_bf + 262144;                    // 131072 bf16 [h][d][l]
    bf16* ckv_bf   = veffT_bf + 131072;                 // 524288 bf16 [b][t][l]
    bf16* ckvT_bf  = ckv_bf + 524288;                   // 524288 bf16 [b][l][t]
    bf16* Q1_bf    = ckvT_bf + 524288;                  // 524288 bf16 [b][t][i]

    k_m1  <<<64,   256, 0, stream>>>(wuq, wuk, M1);
    k_keff<<<512,  256, 0, stream>>>(wdq, M1, keff);
    k_veff<<<512,  256, 0, stream>>>(wuv, wo, veffT_bf);
    k_E   <<<1024, 256, 0, stream>>>(wuq, keff, Et_bf);
    k_ckv <<<2048, 256, 0, stream>>>(x, wdkv, ckv_out, ckv_bf, ckvT_bf);
    k_q1  <<<2048, 256, 0, stream>>>(x, wdq, Q1_bf);

    dim3 grid(TD / 64, NHD, BD);
    k_flash_mfma<<<grid, 256, 0, stream>>>(Q1_bf, Et_bf, ckv_bf, ckvT_bf, veffT_bf, yout);
}

// Round 6
// 411.158 us; speedup vs baseline: 5.9096x; 2.3638x over previous
//
#include <hip/hip_runtime.h>
#include <hip/hip_bf16.h>

typedef __hip_bfloat16 bf16;
typedef __attribute__((ext_vector_type(8))) short short8;
typedef __attribute__((ext_vector_type(4))) float f32x4;

#define NHD 16
#define HSD 64
#define KVLD 128
#define QLD 128
#define CD 1024
#define BD 2
#define TD 2048

__device__ __forceinline__ short8 ld8(const bf16* p) { return *(const short8*)p; }
__device__ __forceinline__ void st8(bf16* p, short8 v) { *(short8*)p = v; }

__device__ __forceinline__ short8 cvt8(float4 a, float4 b) {
    union { short8 s; bf16 h[8]; } u;
    u.h[0] = __float2bfloat16(a.x); u.h[1] = __float2bfloat16(a.y);
    u.h[2] = __float2bfloat16(a.z); u.h[3] = __float2bfloat16(a.w);
    u.h[4] = __float2bfloat16(b.x); u.h[5] = __float2bfloat16(b.y);
    u.h[6] = __float2bfloat16(b.z); u.h[7] = __float2bfloat16(b.w);
    return u.s;
}

// ---------- small precompute GEMMs (weight chain, L2-resident) ----------

// M1[i][j] = sum_c W_uq[c][i] * W_uk[c][j]   (wuq broadcast, wuk coalesced)
__global__ __launch_bounds__(256) void k_m1(const float* __restrict__ wuq,
                                            const float* __restrict__ wuk,
                                            float* __restrict__ m1) {
    int idx = blockIdx.x * 256 + threadIdx.x;
    int i = idx >> 7, j = idx & 127;
    float acc = 0.f;
    for (int c = 0; c < CD; ++c)
        acc += wuq[c * QLD + i] * wuk[c * KVLD + j];
    m1[idx] = acc;
}

// keff[c][j] = sum_i W_dq[i][c] * M1[i][j]   (wdq broadcast, m1 coalesced)
__global__ __launch_bounds__(256) void k_keff(const float* __restrict__ wdq,
                                              const float* __restrict__ m1,
                                              float* __restrict__ keff) {
    int idx = blockIdx.x * 256 + threadIdx.x;
    int c = idx >> 7, j = idx & 127;
    float acc = 0.f;
    for (int i = 0; i < QLD; ++i)
        acc += wdq[i * CD + c] * m1[i * KVLD + j];
    keff[idx] = acc;
}

// veffT_bf[cc][l] = bf16( sum_c0 W_uv[c0][l] * W_o[cc][c0] ), cc = h*64+d
// (wo broadcast per wave, wuv + write coalesced)
__global__ __launch_bounds__(256) void k_veff(const float* __restrict__ wuv,
                                              const float* __restrict__ wo,
                                              bf16* __restrict__ veffT_bf) {
    int idx = blockIdx.x * 256 + threadIdx.x;  // cc*128 + l
    int l = idx & 127;
    int cc = idx >> 7;
    float acc = 0.f;
    for (int c0 = 0; c0 < CD; ++c0)
        acc += wuv[c0 * KVLD + l] * wo[(size_t)cc * CD + c0];
    veffT_bf[idx] = __float2bfloat16(acc);
}

// Et_bf[h][l][i] = bf16( 0.125 * sum_d W_uq[(h*64+d)][i] * keff[(h*64+d)][l] )
// (keff broadcast per wave, wuq + write coalesced)
__global__ __launch_bounds__(256) void k_E(const float* __restrict__ wuq,
                                           const float* __restrict__ keff,
                                           bf16* __restrict__ Et_bf) {
    int idx = blockIdx.x * 256 + threadIdx.x;  // ((h*128+l)*128+i)
    int i = idx & 127;
    int l = (idx >> 7) & 127;
    int h = idx >> 14;
    float acc = 0.f;
    for (int d = 0; d < HSD; ++d)
        acc += wuq[(h * HSD + d) * QLD + i] * keff[(h * HSD + d) * KVLD + l];
    Et_bf[idx] = __float2bfloat16(0.125f * acc);
}

// ---------- fused projection GEMM:  [Q1 | ckv] = x @ [Wdq^T | Wdkv^T] ----------
// BM=64, BN=128, BK=32. Grid (64, 2): y=0 -> Q1, y=1 -> ckv.
// fp32 -> bf16 conversion fused into LDS staging. 4 waves x 16 rows.
__global__ __launch_bounds__(256) void k_proj(const float* __restrict__ x,
                                              const float* __restrict__ wdq,
                                              const float* __restrict__ wdkv,
                                              bf16* __restrict__ q1_bf,
                                              float* __restrict__ ckv_out,
                                              bf16* __restrict__ ckv_bf,
                                              bf16* __restrict__ ckvT_bf) {
    const int m0 = blockIdx.x * 64;
    const int which = blockIdx.y;
    const float* W = which ? wdkv : wdq;
    const int tid = threadIdx.x;
    const int w = tid >> 6, lane = tid & 63, m16 = lane & 15, g = lane >> 4;

    __shared__ __align__(16) short As_raw[64 * 36];
    __shared__ __align__(16) short Bs_raw[128 * 36];
    bf16* As = (bf16*)As_raw;
    bf16* Bs = (bf16*)Bs_raw;

    f32x4 acc[8];
#pragma unroll
    for (int nb = 0; nb < 8; ++nb) acc[nb] = (f32x4){0.f, 0.f, 0.f, 0.f};

    for (int k0 = 0; k0 < CD; k0 += 32) {
        __syncthreads();
        {   // A: 64x32 tile of x
            int row = tid >> 2, kc = (tid & 3) << 3;
            const float* src = x + (size_t)(m0 + row) * CD + k0 + kc;
            float4 f0 = *(const float4*)(src);
            float4 f1 = *(const float4*)(src + 4);
            st8(As + row * 36 + kc, cvt8(f0, f1));
        }
#pragma unroll
        for (int kk = 0; kk < 2; ++kk) {  // B: 128x32 tile of W (rows = out cols)
            int v = tid + kk * 256;
            int row = v >> 2, kc = (v & 3) << 3;
            const float* src = W + (size_t)row * CD + k0 + kc;
            float4 f0 = *(const float4*)(src);
            float4 f1 = *(const float4*)(src + 4);
            st8(Bs + row * 36 + kc, cvt8(f0, f1));
        }
        __syncthreads();
        short8 aF = ld8(As + (w * 16 + m16) * 36 + g * 8);
#pragma unroll
        for (int nb = 0; nb < 8; ++nb) {
            short8 bF = ld8(Bs + (nb * 16 + m16) * 36 + g * 8);
            acc[nb] = __builtin_amdgcn_mfma_f32_16x16x32_bf16(aF, bF, acc[nb], 0, 0, 0);
        }
    }

    // epilogue: C rows = m0 + w*16 + g*4 + r, cols = nb*16 + m16
    if (which == 0) {
#pragma unroll
        for (int nb = 0; nb < 8; ++nb)
#pragma unroll
            for (int r = 0; r < 4; ++r) {
                int t = m0 + w * 16 + g * 4 + r;
                q1_bf[(size_t)t * QLD + nb * 16 + m16] = __float2bfloat16(acc[nb][r]);
            }
    } else {
#pragma unroll
        for (int nb = 0; nb < 8; ++nb)
#pragma unroll
            for (int r = 0; r < 4; ++r) {
                int t = m0 + w * 16 + g * 4 + r;
                int l = nb * 16 + m16;
                float v = acc[nb][r];
                ckv_out[(size_t)t * KVLD + l] = v;
                bf16 hv = __float2bfloat16(v);
                ckv_bf[(size_t)t * KVLD + l] = hv;
                int b = t >> 11, tl = t & 2047;
                ckvT_bf[((size_t)b * KVLD + l) * TD + tl] = hv;
            }
    }
}

// ---------- MFMA flash attention (unchanged from round 5) ----------
__global__ __launch_bounds__(256) void k_flash_mfma(const bf16* __restrict__ Q1_bf,
                                                    const bf16* __restrict__ Et_bf,
                                                    const bf16* __restrict__ ckv_bf,
                                                    const bf16* __restrict__ ckvT_bf,
                                                    const bf16* __restrict__ veffT_bf,
                                                    float* __restrict__ yout) {
    const int qt = blockIdx.x;
    const int h = blockIdx.y;
    const int b = blockIdx.z;
    const int tid = threadIdx.x;
    const int w = tid >> 6;
    const int lane = tid & 63;
    const int m16 = lane & 15;
    const int g = lane >> 4;
    const int row0 = qt * 64;

    __shared__ __align__(16) short smem_raw[26112];
    bf16* smem = (bf16*)smem_raw;
    bf16* Q1t = smem;            // 64 x 136
    bf16* Ets = smem + 8704;     // 128 x 136
    bf16* kvN = smem;            // 64 x 136
    bf16* kvT = smem + 8704;     // 128 x 72
    bf16* pS  = smem + 17920 + w * 1152;  // 16 x 72 per wave
    bf16* ctxS = smem;           // 64 x 136 (epilogue)
    bf16* vT   = smem + 8704;    // 64 x 136 (epilogue)

    {
        const bf16* q1src = Q1_bf + ((size_t)(b * TD + row0)) * QLD;
#pragma unroll
        for (int k = 0; k < 4; ++k) {
            int v = tid + k * 256;
            int row = v >> 4, cv = (v & 15) << 3;
            st8(Q1t + row * 136 + cv, ld8(q1src + row * QLD + cv));
        }
        const bf16* esrc = Et_bf + (size_t)h * QLD * KVLD;
#pragma unroll
        for (int k = 0; k < 8; ++k) {
            int v = tid + k * 256;
            int row = v >> 4, cv = (v & 15) << 3;
            st8(Ets + row * 136 + cv, ld8(esrc + row * QLD + cv));
        }
    }
    __syncthreads();

    f32x4 qc[8];
#pragma unroll
    for (int nb = 0; nb < 8; ++nb) qc[nb] = (f32x4){0.f, 0.f, 0.f, 0.f};
    {
        short8 aq[4];
#pragma unroll
        for (int kf = 0; kf < 4; ++kf)
            aq[kf] = ld8(Q1t + (w * 16 + m16) * 136 + kf * 32 + g * 8);
#pragma unroll
        for (int nb = 0; nb < 8; ++nb)
#pragma unroll
            for (int kf = 0; kf < 4; ++kf) {
                short8 bq = ld8(Ets + (nb * 16 + m16) * 136 + kf * 32 + g * 8);
                qc[nb] = __builtin_amdgcn_mfma_f32_16x16x32_bf16(aq[kf], bq, qc[nb], 0, 0, 0);
            }
    }
    __syncthreads();

#pragma unroll
    for (int nb = 0; nb < 8; ++nb)
#pragma unroll
        for (int r = 0; r < 4; ++r)
            Q1t[(w * 16 + g * 4 + r) * 136 + nb * 16 + m16] = __float2bfloat16(qc[nb][r]);
    __syncthreads();

    short8 qlA[4];
#pragma unroll
    for (int kf = 0; kf < 4; ++kf)
        qlA[kf] = ld8(Q1t + (w * 16 + m16) * 136 + kf * 32 + g * 8);

    f32x4 cx[8];
#pragma unroll
    for (int nb = 0; nb < 8; ++nb) cx[nb] = (f32x4){0.f, 0.f, 0.f, 0.f};
    float mrow[4] = {-INFINITY, -INFINITY, -INFINITY, -INFINITY};
    float lrow[4] = {0.f, 0.f, 0.f, 0.f};

    const bf16* ckb = ckv_bf + (size_t)b * TD * KVLD;
    const bf16* ckTb = ckvT_bf + (size_t)b * KVLD * TD;
    const int nt = qt + 1;

    for (int tile = 0; tile < nt; ++tile) {
        const int s0 = tile * 64;
        const bool diag = (tile == qt);
        __syncthreads();

#pragma unroll
        for (int k = 0; k < 4; ++k) {
            int v = tid + k * 256;
            int row = v >> 4, cv = (v & 15) << 3;
            st8(kvN + row * 136 + cv, ld8(ckb + (size_t)(s0 + row) * KVLD + cv));
        }
#pragma unroll
        for (int k = 0; k < 4; ++k) {
            int v = tid + k * 256;
            int row = v >> 3, cv = (v & 7) << 3;
            st8(kvT + row * 72 + cv, ld8(ckTb + (size_t)row * TD + s0 + cv));
        }
        __syncthreads();

        f32x4 sa[4];
#pragma unroll
        for (int nb = 0; nb < 4; ++nb) sa[nb] = (f32x4){0.f, 0.f, 0.f, 0.f};
#pragma unroll
        for (int nb = 0; nb < 4; ++nb)
#pragma unroll
            for (int kf = 0; kf < 4; ++kf) {
                short8 bk = ld8(kvN + (nb * 16 + m16) * 136 + kf * 32 + g * 8);
                sa[nb] = __builtin_amdgcn_mfma_f32_16x16x32_bf16(qlA[kf], bk, sa[nb], 0, 0, 0);
            }

        if (diag) {
#pragma unroll
            for (int nb = 0; nb < 4; ++nb)
#pragma unroll
                for (int r = 0; r < 4; ++r) {
                    int sg = s0 + nb * 16 + m16;
                    int rg = row0 + w * 16 + g * 4 + r;
                    if (sg > rg) sa[nb][r] = -INFINITY;
                }
        }
        float mt[4], al[4], ps[4];
#pragma unroll
        for (int r = 0; r < 4; ++r) {
            float v = fmaxf(fmaxf(sa[0][r], sa[1][r]), fmaxf(sa[2][r], sa[3][r]));
#pragma unroll
            for (int off = 1; off < 16; off <<= 1)
                v = fmaxf(v, __shfl_xor(v, off));
            mt[r] = fmaxf(mrow[r], v);
            al[r] = __expf(mrow[r] - mt[r]);
            mrow[r] = mt[r];
        }
        float pv[4][4];
#pragma unroll
        for (int nb = 0; nb < 4; ++nb)
#pragma unroll
            for (int r = 0; r < 4; ++r)
                pv[nb][r] = __expf(sa[nb][r] - mt[r]);
#pragma unroll
        for (int r = 0; r < 4; ++r) {
            float v = pv[0][r] + pv[1][r] + pv[2][r] + pv[3][r];
#pragma unroll
            for (int off = 1; off < 16; off <<= 1)
                v += __shfl_xor(v, off);
            ps[r] = v;
            lrow[r] = al[r] * lrow[r] + ps[r];
        }
#pragma unroll
        for (int nb = 0; nb < 8; ++nb)
#pragma unroll
            for (int r = 0; r < 4; ++r)
                cx[nb][r] *= al[r];
#pragma unroll
        for (int nb = 0; nb < 4; ++nb)
#pragma unroll
            for (int r = 0; r < 4; ++r)
                pS[(g * 4 + r) * 72 + nb * 16 + m16] = __float2bfloat16(pv[nb][r]);
        __syncthreads();

        short8 pA[2];
#pragma unroll
        for (int kf = 0; kf < 2; ++kf)
            pA[kf] = ld8(pS + m16 * 72 + kf * 32 + g * 8);
#pragma unroll
        for (int nb = 0; nb < 8; ++nb)
#pragma unroll
            for (int kf = 0; kf < 2; ++kf) {
                short8 bv = ld8(kvT + (nb * 16 + m16) * 72 + kf * 32 + g * 8);
                cx[nb] = __builtin_amdgcn_mfma_f32_16x16x32_bf16(pA[kf], bv, cx[nb], 0, 0, 0);
            }
    }

    float invl[4];
#pragma unroll
    for (int r = 0; r < 4; ++r) invl[r] = 1.f / lrow[r];
#pragma unroll
    for (int nb = 0; nb < 8; ++nb)
#pragma unroll
        for (int r = 0; r < 4; ++r)
            cx[nb][r] *= invl[r];
    __syncthreads();
#pragma unroll
    for (int nb = 0; nb < 8; ++nb)
#pragma unroll
        for (int r = 0; r < 4; ++r)
            ctxS[(w * 16 + g * 4 + r) * 136 + nb * 16 + m16] = __float2bfloat16(cx[nb][r]);
    {
        const bf16* vsrc = veffT_bf + (size_t)h * HSD * KVLD;
#pragma unroll
        for (int k = 0; k < 4; ++k) {
            int v = tid + k * 256;
            int row = v >> 4, cv = (v & 15) << 3;
            st8(vT + row * 136 + cv, ld8(vsrc + row * KVLD + cv));
        }
    }
    __syncthreads();

    f32x4 ya[4];
#pragma unroll
    for (int nb = 0; nb < 4; ++nb) ya[nb] = (f32x4){0.f, 0.f, 0.f, 0.f};
    short8 ca[4];
#pragma unroll
    for (int kf = 0; kf < 4; ++kf)
        ca[kf] = ld8(ctxS + (w * 16 + m16) * 136 + kf * 32 + g * 8);
#pragma unroll
    for (int nb = 0; nb < 4; ++nb)
#pragma unroll
        for (int kf = 0; kf < 4; ++kf) {
            short8 bv = ld8(vT + (nb * 16 + m16) * 136 + kf * 32 + g * 8);
            ya[nb] = __builtin_amdgcn_mfma_f32_16x16x32_bf16(ca[kf], bv, ya[nb], 0, 0, 0);
        }
#pragma unroll
    for (int nb = 0; nb < 4; ++nb)
#pragma unroll
        for (int r = 0; r < 4; ++r) {
            int rg = row0 + w * 16 + g * 4 + r;
            yout[((size_t)b * TD + rg) * CD + h * HSD + nb * 16 + m16] = ya[nb][r];
        }
}

extern "C" void kernel_launch(void* const* d_in, const int* in_sizes, int n_in,
                              void* d_out, int out_size, void* d_ws, size_t ws_size,
                              hipStream_t stream) {
    const float* x    = (const float*)d_in[0];
    const float* wdq  = (const float*)d_in[1];
    const float* wuq  = (const float*)d_in[2];
    const float* wdkv = (const float*)d_in[3];
    const float* wuk  = (const float*)d_in[4];
    const float* wuv  = (const float*)d_in[5];
    const float* wo   = (const float*)d_in[6];
    float* yout = (float*)d_out;                   // (B,T,C) fp32
    float* ckv_out = yout + (size_t)BD * TD * CD;  // (B,T,KVL) fp32

    float* ws = (float*)d_ws;
    float* M1   = ws;                                   // 16384 f
    float* keff = M1 + 16384;                           // 131072 f
    bf16* Et_bf    = (bf16*)(keff + 131072);            // 262144 bf16 [h][l][i]
    bf16* veffT_bf = Et_bf + 262144;                    // 131072 bf16 [h][d][l]
    bf16* ckv_bf   = veffT_bf + 131072;                 // 524288 bf16 [b][t][l]
    bf16* ckvT_bf  = ckv_bf + 524288;                   // 524288 bf16 [b][l][t]
    bf16* Q1_bf    = ckvT_bf + 524288;                  // 524288 bf16 [b][t][i]

    k_m1  <<<64,   256, 0, stream>>>(wuq, wuk, M1);
    k_keff<<<512,  256, 0, stream>>>(wdq, M1, keff);
    k_veff<<<512,  256, 0, stream>>>(wuv, wo, veffT_bf);
    k_E   <<<1024, 256, 0, stream>>>(wuq, keff, Et_bf);

    dim3 pgrid(TD * BD / 64, 2);
    k_proj<<<pgrid, 256, 0, stream>>>(x, wdq, wdkv, Q1_bf, ckv_out, ckv_bf, ckvT_bf);

    dim3 grid(TD / 64, NHD, BD);
    k_flash_mfma<<<grid, 256, 0, stream>>>(Q1_bf, Et_bf, ckv_bf, ckvT_bf, veffT_bf, yout);
}

// Round 7
// 359.985 us; speedup vs baseline: 6.7497x; 1.1422x over previous
//
#include <hip/hip_runtime.h>
#include <hip/hip_bf16.h>

typedef __hip_bfloat16 bf16;
typedef __attribute__((ext_vector_type(8))) short short8;
typedef __attribute__((ext_vector_type(4))) float f32x4;

#define NHD 16
#define HSD 64
#define KVLD 128
#define QLD 128
#define CD 1024
#define BD 2
#define TD 2048

__device__ __forceinline__ short8 ld8(const bf16* p) { return *(const short8*)p; }
__device__ __forceinline__ void st8(bf16* p, short8 v) { *(short8*)p = v; }

__device__ __forceinline__ short8 cvt8(float4 a, float4 b) {
    union { short8 s; bf16 h[8]; } u;
    u.h[0] = __float2bfloat16(a.x); u.h[1] = __float2bfloat16(a.y);
    u.h[2] = __float2bfloat16(a.z); u.h[3] = __float2bfloat16(a.w);
    u.h[4] = __float2bfloat16(b.x); u.h[5] = __float2bfloat16(b.y);
    u.h[6] = __float2bfloat16(b.z); u.h[7] = __float2bfloat16(b.w);
    return u.s;
}

// ---------- small precompute GEMMs (weight chain, L2-resident) ----------

__global__ __launch_bounds__(256) void k_m1(const float* __restrict__ wuq,
                                            const float* __restrict__ wuk,
                                            float* __restrict__ m1) {
    int idx = blockIdx.x * 256 + threadIdx.x;
    int i = idx >> 7, j = idx & 127;
    float acc = 0.f;
    for (int c = 0; c < CD; ++c)
        acc += wuq[c * QLD + i] * wuk[c * KVLD + j];
    m1[idx] = acc;
}

__global__ __launch_bounds__(256) void k_keff(const float* __restrict__ wdq,
                                              const float* __restrict__ m1,
                                              float* __restrict__ keff) {
    int idx = blockIdx.x * 256 + threadIdx.x;
    int c = idx >> 7, j = idx & 127;
    float acc = 0.f;
    for (int i = 0; i < QLD; ++i)
        acc += wdq[i * CD + c] * m1[i * KVLD + j];
    keff[idx] = acc;
}

__global__ __launch_bounds__(256) void k_veff(const float* __restrict__ wuv,
                                              const float* __restrict__ wo,
                                              bf16* __restrict__ veffT_bf) {
    int idx = blockIdx.x * 256 + threadIdx.x;  // cc*128 + l
    int l = idx & 127;
    int cc = idx >> 7;
    float acc = 0.f;
    for (int c0 = 0; c0 < CD; ++c0)
        acc += wuv[c0 * KVLD + l] * wo[(size_t)cc * CD + c0];
    veffT_bf[idx] = __float2bfloat16(acc);
}

// Et scale = 0.125 * log2(e) so softmax can run in exp2 domain
__global__ __launch_bounds__(256) void k_E(const float* __restrict__ wuq,
                                           const float* __restrict__ keff,
                                           bf16* __restrict__ Et_bf) {
    int idx = blockIdx.x * 256 + threadIdx.x;  // ((h*128+l)*128+i)
    int i = idx & 127;
    int l = (idx >> 7) & 127;
    int h = idx >> 14;
    float acc = 0.f;
    for (int d = 0; d < HSD; ++d)
        acc += wuq[(h * HSD + d) * QLD + i] * keff[(h * HSD + d) * KVLD + l];
    Et_bf[idx] = __float2bfloat16(0.1803368801f * acc);
}

// ---------- fused projection GEMM: [Q1 | ckv] = x @ [Wdq | Wdkv]^T ----------
// BM=64, BN=256 (128 Q1 + 128 ckv), BK=64. Grid 64. 4 waves x 16 rows.
__global__ __launch_bounds__(256) void k_proj(const float* __restrict__ x,
                                              const float* __restrict__ wdq,
                                              const float* __restrict__ wdkv,
                                              bf16* __restrict__ q1_bf,
                                              float* __restrict__ ckv_out,
                                              bf16* __restrict__ ckv_bf,
                                              bf16* __restrict__ ckvT_bf) {
    const int m0 = blockIdx.x * 64;
    const int tid = threadIdx.x;
    const int w = tid >> 6, lane = tid & 63, m16 = lane & 15, g = lane >> 4;

    __shared__ __align__(16) short As_raw[64 * 72];
    __shared__ __align__(16) short Bs_raw[256 * 72];
    bf16* As = (bf16*)As_raw;
    bf16* Bs = (bf16*)Bs_raw;

    f32x4 acc[16];
#pragma unroll
    for (int nb = 0; nb < 16; ++nb) acc[nb] = (f32x4){0.f, 0.f, 0.f, 0.f};

    for (int k0 = 0; k0 < CD; k0 += 64) {
        __syncthreads();
#pragma unroll
        for (int kk = 0; kk < 2; ++kk) {  // A: 64x64 tile of x
            int v = tid + kk * 256;
            int row = v >> 3, kc = (v & 7) << 3;
            const float* src = x + (size_t)(m0 + row) * CD + k0 + kc;
            float4 f0 = *(const float4*)(src);
            float4 f1 = *(const float4*)(src + 4);
            st8(As + row * 72 + kc, cvt8(f0, f1));
        }
#pragma unroll
        for (int kk = 0; kk < 8; ++kk) {  // B: 256x64 (rows 0-127 wdq, 128-255 wdkv)
            int v = tid + kk * 256;
            int row = v >> 3, kc = (v & 7) << 3;
            const float* wr = (row < 128) ? (wdq + (size_t)row * CD)
                                          : (wdkv + (size_t)(row - 128) * CD);
            const float* src = wr + k0 + kc;
            float4 f0 = *(const float4*)(src);
            float4 f1 = *(const float4*)(src + 4);
            st8(Bs + row * 72 + kc, cvt8(f0, f1));
        }
        __syncthreads();
        short8 aF[2];
#pragma unroll
        for (int kf = 0; kf < 2; ++kf)
            aF[kf] = ld8(As + (w * 16 + m16) * 72 + kf * 32 + g * 8);
#pragma unroll
        for (int nb = 0; nb < 16; ++nb)
#pragma unroll
            for (int kf = 0; kf < 2; ++kf) {
                short8 bF = ld8(Bs + (nb * 16 + m16) * 72 + kf * 32 + g * 8);
                acc[nb] = __builtin_amdgcn_mfma_f32_16x16x32_bf16(aF[kf], bF, acc[nb], 0, 0, 0);
            }
    }

#pragma unroll
    for (int nb = 0; nb < 16; ++nb)
#pragma unroll
        for (int r = 0; r < 4; ++r) {
            int t = m0 + w * 16 + g * 4 + r;
            int col = nb * 16 + m16;
            float v = acc[nb][r];
            if (col < 128) {
                q1_bf[(size_t)t * QLD + col] = __float2bfloat16(v);
            } else {
                int l = col - 128;
                ckv_out[(size_t)t * KVLD + l] = v;
                bf16 hv = __float2bfloat16(v);
                ckv_bf[(size_t)t * KVLD + l] = hv;
                int b = t >> 11, tl = t & 2047;
                ckvT_bf[((size_t)b * KVLD + l) * TD + tl] = hv;
            }
        }
}

// ---------- MFMA flash attention, paired q-tiles for load balance ----------
// Block = (qtp, h, b) handles q-tiles qtp and 31-qtp -> exactly 33 KV-tiles each.
__global__ __launch_bounds__(256) void k_flash_mfma(const bf16* __restrict__ Q1_bf,
                                                    const bf16* __restrict__ Et_bf,
                                                    const bf16* __restrict__ ckv_bf,
                                                    const bf16* __restrict__ ckvT_bf,
                                                    const bf16* __restrict__ veffT_bf,
                                                    float* __restrict__ yout) {
    const int qtp = blockIdx.x;  // 0..15
    const int h = blockIdx.y;
    const int b = blockIdx.z;
    const int tid = threadIdx.x;
    const int w = tid >> 6;
    const int lane = tid & 63;
    const int m16 = lane & 15;
    const int g = lane >> 4;

    __shared__ __align__(16) short smem_raw[26112];
    bf16* smem = (bf16*)smem_raw;
    bf16* Q1t = smem;            // 64 x 136
    bf16* Ets = smem + 8704;     // 128 x 136
    bf16* kvN = smem;            // 64 x 136
    bf16* kvT = smem + 8704;     // 128 x 72
    bf16* pS  = smem + 17920 + w * 1152;  // 16 x 72 per wave
    bf16* ctxS = smem;           // 64 x 136 (epilogue)
    bf16* vT   = smem + 8704;    // 64 x 136 (epilogue)

    const bf16* ckb = ckv_bf + (size_t)b * TD * KVLD;
    const bf16* ckTb = ckvT_bf + (size_t)b * KVLD * TD;

    for (int half = 0; half < 2; ++half) {
        const int qt = half ? (31 - qtp) : qtp;
        const int row0 = qt * 64;

        __syncthreads();  // protect previous half's epilogue LDS reads
        {
            const bf16* q1src = Q1_bf + ((size_t)(b * TD + row0)) * QLD;
#pragma unroll
            for (int k = 0; k < 4; ++k) {
                int v = tid + k * 256;
                int row = v >> 4, cv = (v & 15) << 3;
                st8(Q1t + row * 136 + cv, ld8(q1src + row * QLD + cv));
            }
            const bf16* esrc = Et_bf + (size_t)h * QLD * KVLD;
#pragma unroll
            for (int k = 0; k < 8; ++k) {
                int v = tid + k * 256;
                int row = v >> 4, cv = (v & 15) << 3;
                st8(Ets + row * 136 + cv, ld8(esrc + row * QLD + cv));
            }
        }
        __syncthreads();

        f32x4 qc[8];
#pragma unroll
        for (int nb = 0; nb < 8; ++nb) qc[nb] = (f32x4){0.f, 0.f, 0.f, 0.f};
        {
            short8 aq[4];
#pragma unroll
            for (int kf = 0; kf < 4; ++kf)
                aq[kf] = ld8(Q1t + (w * 16 + m16) * 136 + kf * 32 + g * 8);
#pragma unroll
            for (int nb = 0; nb < 8; ++nb)
#pragma unroll
                for (int kf = 0; kf < 4; ++kf) {
                    short8 bq = ld8(Ets + (nb * 16 + m16) * 136 + kf * 32 + g * 8);
                    qc[nb] = __builtin_amdgcn_mfma_f32_16x16x32_bf16(aq[kf], bq, qc[nb], 0, 0, 0);
                }
        }
        __syncthreads();

#pragma unroll
        for (int nb = 0; nb < 8; ++nb)
#pragma unroll
            for (int r = 0; r < 4; ++r)
                Q1t[(w * 16 + g * 4 + r) * 136 + nb * 16 + m16] = __float2bfloat16(qc[nb][r]);
        __syncthreads();

        short8 qlA[4];
#pragma unroll
        for (int kf = 0; kf < 4; ++kf)
            qlA[kf] = ld8(Q1t + (w * 16 + m16) * 136 + kf * 32 + g * 8);

        f32x4 cx[8];
#pragma unroll
        for (int nb = 0; nb < 8; ++nb) cx[nb] = (f32x4){0.f, 0.f, 0.f, 0.f};
        float mrow[4] = {-INFINITY, -INFINITY, -INFINITY, -INFINITY};
        float lrow[4] = {0.f, 0.f, 0.f, 0.f};

        const int nt = qt + 1;
        for (int tile = 0; tile < nt; ++tile) {
            const int s0 = tile * 64;
            const bool diag = (tile == qt);
            __syncthreads();

#pragma unroll
            for (int k = 0; k < 4; ++k) {
                int v = tid + k * 256;
                int row = v >> 4, cv = (v & 15) << 3;
                st8(kvN + row * 136 + cv, ld8(ckb + (size_t)(s0 + row) * KVLD + cv));
            }
#pragma unroll
            for (int k = 0; k < 4; ++k) {
                int v = tid + k * 256;
                int row = v >> 3, cv = (v & 7) << 3;
                st8(kvT + row * 72 + cv, ld8(ckTb + (size_t)row * TD + s0 + cv));
            }
            __syncthreads();

            f32x4 sa[4];
#pragma unroll
            for (int nb = 0; nb < 4; ++nb) sa[nb] = (f32x4){0.f, 0.f, 0.f, 0.f};
#pragma unroll
            for (int nb = 0; nb < 4; ++nb)
#pragma unroll
                for (int kf = 0; kf < 4; ++kf) {
                    short8 bk = ld8(kvN + (nb * 16 + m16) * 136 + kf * 32 + g * 8);
                    sa[nb] = __builtin_amdgcn_mfma_f32_16x16x32_bf16(qlA[kf], bk, sa[nb], 0, 0, 0);
                }

            if (diag) {
#pragma unroll
                for (int nb = 0; nb < 4; ++nb)
#pragma unroll
                    for (int r = 0; r < 4; ++r) {
                        int sg = s0 + nb * 16 + m16;
                        int rg = row0 + w * 16 + g * 4 + r;
                        if (sg > rg) sa[nb][r] = -INFINITY;
                    }
            }
            float mt[4], al[4];
#pragma unroll
            for (int r = 0; r < 4; ++r) {
                float v = fmaxf(fmaxf(sa[0][r], sa[1][r]), fmaxf(sa[2][r], sa[3][r]));
#pragma unroll
                for (int off = 1; off < 16; off <<= 1)
                    v = fmaxf(v, __shfl_xor(v, off));
                mt[r] = fmaxf(mrow[r], v);
                al[r] = exp2f(mrow[r] - mt[r]);   // exp2 domain (log2e folded into Et)
                mrow[r] = mt[r];
            }
            float pv[4][4];
#pragma unroll
            for (int nb = 0; nb < 4; ++nb)
#pragma unroll
                for (int r = 0; r < 4; ++r)
                    pv[nb][r] = exp2f(sa[nb][r] - mt[r]);
#pragma unroll
            for (int r = 0; r < 4; ++r) {
                float v = pv[0][r] + pv[1][r] + pv[2][r] + pv[3][r];
#pragma unroll
                for (int off = 1; off < 16; off <<= 1)
                    v += __shfl_xor(v, off);
                lrow[r] = al[r] * lrow[r] + v;
            }
#pragma unroll
            for (int nb = 0; nb < 8; ++nb)
#pragma unroll
                for (int r = 0; r < 4; ++r)
                    cx[nb][r] *= al[r];
#pragma unroll
            for (int nb = 0; nb < 4; ++nb)
#pragma unroll
                for (int r = 0; r < 4; ++r)
                    pS[(g * 4 + r) * 72 + nb * 16 + m16] = __float2bfloat16(pv[nb][r]);
            __syncthreads();

            short8 pA[2];
#pragma unroll
            for (int kf = 0; kf < 2; ++kf)
                pA[kf] = ld8(pS + m16 * 72 + kf * 32 + g * 8);
#pragma unroll
            for (int nb = 0; nb < 8; ++nb)
#pragma unroll
                for (int kf = 0; kf < 2; ++kf) {
                    short8 bv = ld8(kvT + (nb * 16 + m16) * 72 + kf * 32 + g * 8);
                    cx[nb] = __builtin_amdgcn_mfma_f32_16x16x32_bf16(pA[kf], bv, cx[nb], 0, 0, 0);
                }
        }

        // epilogue: y = (ctx / l) @ veff
        float invl[4];
#pragma unroll
        for (int r = 0; r < 4; ++r) invl[r] = 1.f / lrow[r];
#pragma unroll
        for (int nb = 0; nb < 8; ++nb)
#pragma unroll
            for (int r = 0; r < 4; ++r)
                cx[nb][r] *= invl[r];
        __syncthreads();
#pragma unroll
        for (int nb = 0; nb < 8; ++nb)
#pragma unroll
            for (int r = 0; r < 4; ++r)
                ctxS[(w * 16 + g * 4 + r) * 136 + nb * 16 + m16] = __float2bfloat16(cx[nb][r]);
        {
            const bf16* vsrc = veffT_bf + (size_t)h * HSD * KVLD;
#pragma unroll
            for (int k = 0; k < 4; ++k) {
                int v = tid + k * 256;
                int row = v >> 4, cv = (v & 15) << 3;
                st8(vT + row * 136 + cv, ld8(vsrc + row * KVLD + cv));
            }
        }
        __syncthreads();

        f32x4 ya[4];
#pragma unroll
        for (int nb = 0; nb < 4; ++nb) ya[nb] = (f32x4){0.f, 0.f, 0.f, 0.f};
        short8 ca[4];
#pragma unroll
        for (int kf = 0; kf < 4; ++kf)
            ca[kf] = ld8(ctxS + (w * 16 + m16) * 136 + kf * 32 + g * 8);
#pragma unroll
        for (int nb = 0; nb < 4; ++nb)
#pragma unroll
            for (int kf = 0; kf < 4; ++kf) {
                short8 bv = ld8(vT + (nb * 16 + m16) * 136 + kf * 32 + g * 8);
                ya[nb] = __builtin_amdgcn_mfma_f32_16x16x32_bf16(ca[kf], bv, ya[nb], 0, 0, 0);
            }
#pragma unroll
        for (int nb = 0; nb < 4; ++nb)
#pragma unroll
            for (int r = 0; r < 4; ++r) {
                int rg = row0 + w * 16 + g * 4 + r;
                yout[((size_t)b * TD + rg) * CD + h * HSD + nb * 16 + m16] = ya[nb][r];
            }
    }
}

extern "C" void kernel_launch(void* const* d_in, const int* in_sizes, int n_in,
                              void* d_out, int out_size, void* d_ws, size_t ws_size,
                              hipStream_t stream) {
    const float* x    = (const float*)d_in[0];
    const float* wdq  = (const float*)d_in[1];
    const float* wuq  = (const float*)d_in[2];
    const float* wdkv = (const float*)d_in[3];
    const float* wuk  = (const float*)d_in[4];
    const float* wuv  = (const float*)d_in[5];
    const float* wo   = (const float*)d_in[6];
    float* yout = (float*)d_out;                   // (B,T,C) fp32
    float* ckv_out = yout + (size_t)BD * TD * CD;  // (B,T,KVL) fp32

    float* ws = (float*)d_ws;
    float* M1   = ws;                                   // 16384 f
    float* keff = M1 + 16384;                           // 131072 f
    bf16* Et_bf    = (bf16*)(keff + 131072);            // 262144 bf16 [h][l][i]
    bf16* veffT_bf = Et_bf + 262144;                    // 131072 bf16 [h*64+d][l]
    bf16* ckv_bf   = veffT_bf + 131072;                 // 524288 bf16 [b][t][l]
    bf16* ckvT_bf  = ckv_bf + 524288;                   // 524288 bf16 [b][l][t]
    bf16* Q1_bf    = ckvT_bf + 524288;                  // 524288 bf16 [b][t][i]

    k_m1  <<<64,   256, 0, stream>>>(wuq, wuk, M1);
    k_keff<<<512,  256, 0, stream>>>(wdq, M1, keff);
    k_veff<<<512,  256, 0, stream>>>(wuv, wo, veffT_bf);
    k_E   <<<1024, 256, 0, stream>>>(wuq, keff, Et_bf);

    k_proj<<<TD * BD / 64, 256, 0, stream>>>(x, wdq, wdkv, Q1_bf, ckv_out, ckv_bf, ckvT_bf);

    dim3 grid(16, NHD, BD);
    k_flash_mfma<<<grid, 256, 0, stream>>>(Q1_bf, Et_bf, ckv_bf, ckvT_bf, veffT_bf, yout);
}

// Round 9
// 287.104 us; speedup vs baseline: 8.4631x; 1.2538x over previous
//
#include <hip/hip_runtime.h>
#include <hip/hip_bf16.h>

typedef __hip_bfloat16 bf16;
typedef __attribute__((ext_vector_type(8))) short short8;
typedef __attribute__((ext_vector_type(4))) float f32x4;

#define NHD 16
#define HSD 64
#define KVLD 128
#define QLD 128
#define CD 1024
#define BD 2
#define TD 2048

__device__ __forceinline__ short8 ld8(const bf16* p) { return *(const short8*)p; }
__device__ __forceinline__ void st8(bf16* p, short8 v) { *(short8*)p = v; }

__device__ __forceinline__ short8 cvt8(float4 a, float4 b) {
    union { short8 s; bf16 h[8]; } u;
    u.h[0] = __float2bfloat16(a.x); u.h[1] = __float2bfloat16(a.y);
    u.h[2] = __float2bfloat16(a.z); u.h[3] = __float2bfloat16(a.w);
    u.h[4] = __float2bfloat16(b.x); u.h[5] = __float2bfloat16(b.y);
    u.h[6] = __float2bfloat16(b.z); u.h[7] = __float2bfloat16(b.w);
    return u.s;
}
__device__ __forceinline__ void st4(bf16* p, float4 a) {
    union { short4 s; bf16 h[4]; } u;
    u.h[0] = __float2bfloat16(a.x); u.h[1] = __float2bfloat16(a.y);
    u.h[2] = __float2bfloat16(a.z); u.h[3] = __float2bfloat16(a.w);
    *(short4*)p = u.s;
}

// ---------- weight-chain precompute ----------

// M1 partials: K split 8 ways (grid (64,8))
__global__ __launch_bounds__(256) void k_m1p(const float* __restrict__ wuq,
                                             const float* __restrict__ wuk,
                                             float* __restrict__ m1p) {
    int idx = blockIdx.x * 256 + threadIdx.x;
    int i = idx >> 7, j = idx & 127;
    int c0 = blockIdx.y * 128;
    float acc = 0.f;
    for (int c = c0; c < c0 + 128; ++c)
        acc += wuq[c * QLD + i] * wuk[c * KVLD + j];
    m1p[blockIdx.y * 16384 + idx] = acc;
}

__global__ __launch_bounds__(256) void k_m1r(const float* __restrict__ m1p,
                                             float* __restrict__ m1) {
    int idx = blockIdx.x * 256 + threadIdx.x;
    float acc = 0.f;
#pragma unroll
    for (int p = 0; p < 8; ++p) acc += m1p[p * 16384 + idx];
    m1[idx] = acc;
}

__global__ __launch_bounds__(256) void k_keff(const float* __restrict__ wdq,
                                              const float* __restrict__ m1,
                                              float* __restrict__ keff) {
    int idx = blockIdx.x * 256 + threadIdx.x;
    int c = idx >> 7, j = idx & 127;
    float acc = 0.f;
    for (int i = 0; i < QLD; ++i)
        acc += wdq[i * CD + c] * m1[i * KVLD + j];
    keff[idx] = acc;
}

__global__ __launch_bounds__(256) void k_veff(const float* __restrict__ wuv,
                                              const float* __restrict__ wo,
                                              bf16* __restrict__ veffT_bf) {
    int idx = blockIdx.x * 256 + threadIdx.x;  // cc*128 + l
    int l = idx & 127;
    int cc = idx >> 7;
    float acc = 0.f;
    for (int c0 = 0; c0 < CD; ++c0)
        acc += wuv[c0 * KVLD + l] * wo[(size_t)cc * CD + c0];
    veffT_bf[idx] = __float2bfloat16(acc);
}

// Et scale = 0.125 * log2(e): softmax runs in exp2 domain
__global__ __launch_bounds__(256) void k_E(const float* __restrict__ wuq,
                                           const float* __restrict__ keff,
                                           bf16* __restrict__ Et_bf) {
    int idx = blockIdx.x * 256 + threadIdx.x;  // ((h*128+l)*128+i)
    int i = idx & 127;
    int l = (idx >> 7) & 127;
    int h = idx >> 14;
    float acc = 0.f;
    for (int d = 0; d < HSD; ++d)
        acc += wuq[(h * HSD + d) * QLD + i] * keff[(h * HSD + d) * KVLD + l];
    Et_bf[idx] = __float2bfloat16(0.1803368801f * acc);
}

// ---------- fused projection GEMM: [Q1 | ckv] = x @ [Wdq | Wdkv]^T ----------
// BM=16, BN=256, BK=64. Grid 256. Wave w handles cols [w*64, w*64+64).
__global__ __launch_bounds__(256) void k_proj(const float* __restrict__ x,
                                              const float* __restrict__ wdq,
                                              const float* __restrict__ wdkv,
                                              bf16* __restrict__ q1_bf,
                                              float* __restrict__ ckv_out,
                                              bf16* __restrict__ ckv_bf,
                                              bf16* __restrict__ ckvT_bf) {
    const int m0 = blockIdx.x * 16;
    const int tid = threadIdx.x;
    const int w = tid >> 6, lane = tid & 63, m16 = lane & 15, g = lane >> 4;

    __shared__ __align__(16) short As_raw[16 * 72];
    __shared__ __align__(16) short Bs_raw[256 * 72];
    bf16* As = (bf16*)As_raw;
    bf16* Bs = (bf16*)Bs_raw;

    f32x4 acc[4];
#pragma unroll
    for (int nb = 0; nb < 4; ++nb) acc[nb] = (f32x4){0.f, 0.f, 0.f, 0.f};

    for (int k0 = 0; k0 < CD; k0 += 64) {
        __syncthreads();
        {   // A: 16x64 tile of x
            int row = tid >> 4, kc = (tid & 15) << 2;
            float4 f = *(const float4*)(x + (size_t)(m0 + row) * CD + k0 + kc);
            st4(As + row * 72 + kc, f);
        }
#pragma unroll
        for (int kk = 0; kk < 8; ++kk) {  // B: 256x64 (rows 0-127 wdq, 128-255 wdkv)
            int v = tid + kk * 256;
            int row = v >> 3, kc = (v & 7) << 3;
            const float* wr = (row < 128) ? (wdq + (size_t)row * CD)
                                          : (wdkv + (size_t)(row - 128) * CD);
            const float* src = wr + k0 + kc;
            float4 f0 = *(const float4*)(src);
            float4 f1 = *(const float4*)(src + 4);
            st8(Bs + row * 72 + kc, cvt8(f0, f1));
        }
        __syncthreads();
        short8 aF[2];
#pragma unroll
        for (int kf = 0; kf < 2; ++kf)
            aF[kf] = ld8(As + m16 * 72 + kf * 32 + g * 8);
#pragma unroll
        for (int nb = 0; nb < 4; ++nb)
#pragma unroll
            for (int kf = 0; kf < 2; ++kf) {
                short8 bF = ld8(Bs + (w * 64 + nb * 16 + m16) * 72 + kf * 32 + g * 8);
                acc[nb] = __builtin_amdgcn_mfma_f32_16x16x32_bf16(aF[kf], bF, acc[nb], 0, 0, 0);
            }
    }

#pragma unroll
    for (int nb = 0; nb < 4; ++nb)
#pragma unroll
        for (int r = 0; r < 4; ++r) {
            int t = m0 + g * 4 + r;
            int col = w * 64 + nb * 16 + m16;
            float v = acc[nb][r];
            if (col < 128) {
                q1_bf[(size_t)t * QLD + col] = __float2bfloat16(v);
            } else {
                int l = col - 128;
                ckv_out[(size_t)t * KVLD + l] = v;
                bf16 hv = __float2bfloat16(v);
                ckv_bf[(size_t)t * KVLD + l] = hv;
                int b = t >> 11, tl = t & 2047;
                ckvT_bf[((size_t)b * KVLD + l) * TD + tl] = hv;
            }
        }
}

// ---------- MFMA flash attention ----------
// Grid (32 hb, 32): qt = 31 - blockIdx.y (heavy blocks dispatch first, LPT).
// LDS (shorts): [0,8704) kvN 64x136 | [8704,19072) kvT 144x72 (rows 128..143 = ALL ones)
//               [19072,23680) pS 4 x 16x72.  Total 47360 B -> 3 blocks/CU.
// Rowsum trick: PV nb=8 multiplies by all-ones rows -> every lane's cx[8][r] is the
// running softmax denominator (all 16 cols of the block identical). The previous
// [ones|zeros] variant left the sum only in col 128 (m16==0) -> div-by-zero NaN.
__global__ __launch_bounds__(256, 3) void k_flash(const bf16* __restrict__ Q1_bf,
                                                  const bf16* __restrict__ Et_bf,
                                                  const bf16* __restrict__ ckv_bf,
                                                  const bf16* __restrict__ ckvT_bf,
                                                  const bf16* __restrict__ veffT_bf,
                                                  float* __restrict__ yout) {
    const int h = blockIdx.x & 15;
    const int b = blockIdx.x >> 4;
    const int qt = 31 - blockIdx.y;
    const int tid = threadIdx.x;
    const int w = tid >> 6;
    const int lane = tid & 63;
    const int m16 = lane & 15;
    const int g = lane >> 4;
    const int row0 = qt * 64;

    __shared__ __align__(16) short smem_raw[23680];
    bf16* smem = (bf16*)smem_raw;
    bf16* kvN = smem;             // 64 x 136
    bf16* kvT = smem + 8704;      // 144 x 72
    bf16* pS  = smem + 19072 + w * 1152;  // 16 x 72 per wave
    bf16* qlS = smem + 8704;      // prologue alias: 64 x 136 (rows 0..63 of kvT region)
    bf16* ctxS = smem;            // epilogue alias
    bf16* vT   = smem + 8704;     // epilogue alias: 64 x 136

    // all-ones rows of kvT (l = 128..143), written once
    {
        const bf16 one = __float2bfloat16(1.0f);
        for (int i = tid; i < 16 * 72; i += 256)
            kvT[9216 + i] = one;
    }

    // ---- prologue: ql = Q1_tile @ E[h], E B-frags from global ----
    {
        const bf16* q1src = Q1_bf + ((size_t)(b * TD + row0)) * QLD;
#pragma unroll
        for (int k = 0; k < 4; ++k) {
            int v = tid + k * 256;
            int row = v >> 4, cv = (v & 15) << 3;
            st8(kvN + row * 136 + cv, ld8(q1src + row * QLD + cv));
        }
    }
    __syncthreads();
    {
        short8 aq[4];
#pragma unroll
        for (int kf = 0; kf < 4; ++kf)
            aq[kf] = ld8(kvN + (w * 16 + m16) * 136 + kf * 32 + g * 8);
        const bf16* Eh = Et_bf + (size_t)h * QLD * KVLD;
        f32x4 qc[8];
#pragma unroll
        for (int nb = 0; nb < 8; ++nb) qc[nb] = (f32x4){0.f, 0.f, 0.f, 0.f};
#pragma unroll
        for (int nb = 0; nb < 8; ++nb)
#pragma unroll
            for (int kf = 0; kf < 4; ++kf) {
                short8 bq = ld8(Eh + (nb * 16 + m16) * QLD + kf * 32 + g * 8);
                qc[nb] = __builtin_amdgcn_mfma_f32_16x16x32_bf16(aq[kf], bq, qc[nb], 0, 0, 0);
            }
        // write ql tile to LDS (disjoint from kvN), then reload as A-frags
#pragma unroll
        for (int nb = 0; nb < 8; ++nb)
#pragma unroll
            for (int r = 0; r < 4; ++r)
                qlS[(w * 16 + g * 4 + r) * 136 + nb * 16 + m16] = __float2bfloat16(qc[nb][r]);
    }
    __syncthreads();
    short8 qlA[4];
#pragma unroll
    for (int kf = 0; kf < 4; ++kf)
        qlA[kf] = ld8(qlS + (w * 16 + m16) * 136 + kf * 32 + g * 8);

    // ---- main loop ----
    f32x4 cx[9];
#pragma unroll
    for (int nb = 0; nb < 9; ++nb) cx[nb] = (f32x4){0.f, 0.f, 0.f, 0.f};
    float mrow[4] = {-INFINITY, -INFINITY, -INFINITY, -INFINITY};

    const bf16* ckb = ckv_bf + (size_t)b * TD * KVLD;
    const bf16* ckTb = ckvT_bf + (size_t)b * KVLD * TD;

    int nrow[4], ncol[4], trow[4], tcol[4];
#pragma unroll
    for (int k = 0; k < 4; ++k) {
        int v = tid + k * 256;
        nrow[k] = v >> 4; ncol[k] = (v & 15) << 3;
        trow[k] = v >> 3; tcol[k] = (v & 7) << 3;
    }
    short8 pfN[4], pfT[4];
#pragma unroll
    for (int k = 0; k < 4; ++k) {   // prefetch tile 0
        pfN[k] = ld8(ckb + (size_t)nrow[k] * KVLD + ncol[k]);
        pfT[k] = ld8(ckTb + (size_t)trow[k] * TD + tcol[k]);
    }

    for (int tile = 0; tile <= qt; ++tile) {
        const int s0 = tile * 64;
        const bool diag = (tile == qt);
        __syncthreads();  // previous iter's LDS reads (and prologue qlA reads) done
#pragma unroll
        for (int k = 0; k < 4; ++k) {
            st8(kvN + nrow[k] * 136 + ncol[k], pfN[k]);
            st8(kvT + trow[k] * 72 + tcol[k], pfT[k]);
        }
        __syncthreads();
        if (tile < qt) {
            const int s1 = s0 + 64;
#pragma unroll
            for (int k = 0; k < 4; ++k) {
                pfN[k] = ld8(ckb + (size_t)(s1 + nrow[k]) * KVLD + ncol[k]);
                pfT[k] = ld8(ckTb + (size_t)trow[k] * TD + s1 + tcol[k]);
            }
        }

        // S = ql @ kv^T (16x64 per wave)
        f32x4 sa[4];
#pragma unroll
        for (int nb = 0; nb < 4; ++nb) sa[nb] = (f32x4){0.f, 0.f, 0.f, 0.f};
#pragma unroll
        for (int nb = 0; nb < 4; ++nb)
#pragma unroll
            for (int kf = 0; kf < 4; ++kf) {
                short8 bk = ld8(kvN + (nb * 16 + m16) * 136 + kf * 32 + g * 8);
                sa[nb] = __builtin_amdgcn_mfma_f32_16x16x32_bf16(qlA[kf], bk, sa[nb], 0, 0, 0);
            }

        if (diag) {
#pragma unroll
            for (int nb = 0; nb < 4; ++nb)
#pragma unroll
                for (int r = 0; r < 4; ++r) {
                    int sg = s0 + nb * 16 + m16;
                    int rg = row0 + w * 16 + g * 4 + r;
                    if (sg > rg) sa[nb][r] = -INFINITY;
                }
        }
        float mt[4], al[4];
#pragma unroll
        for (int r = 0; r < 4; ++r) {
            float v = fmaxf(fmaxf(sa[0][r], sa[1][r]), fmaxf(sa[2][r], sa[3][r]));
#pragma unroll
            for (int off = 1; off < 16; off <<= 1)
                v = fmaxf(v, __shfl_xor(v, off));
            mt[r] = fmaxf(mrow[r], v);
            al[r] = exp2f(mrow[r] - mt[r]);
            mrow[r] = mt[r];
        }
#pragma unroll
        for (int nb = 0; nb < 9; ++nb)
#pragma unroll
            for (int r = 0; r < 4; ++r)
                cx[nb][r] *= al[r];
#pragma unroll
        for (int nb = 0; nb < 4; ++nb)
#pragma unroll
            for (int r = 0; r < 4; ++r)
                pS[(g * 4 + r) * 72 + nb * 16 + m16] =
                    __float2bfloat16(exp2f(sa[nb][r] - mt[r]));
        __builtin_amdgcn_wave_barrier();  // pS is per-wave; lgkmcnt drain ordered by compiler

        // ctx += P @ kv ; nb=8 accumulates the row-sum (denominator)
        short8 pA[2];
#pragma unroll
        for (int kf = 0; kf < 2; ++kf)
            pA[kf] = ld8(pS + m16 * 72 + kf * 32 + g * 8);
#pragma unroll
        for (int nb = 0; nb < 9; ++nb)
#pragma unroll
            for (int kf = 0; kf < 2; ++kf) {
                short8 bv = ld8(kvT + (nb * 16 + m16) * 72 + kf * 32 + g * 8);
                cx[nb] = __builtin_amdgcn_mfma_f32_16x16x32_bf16(pA[kf], bv, cx[nb], 0, 0, 0);
            }
    }

    // ---- epilogue: y = (ctx / l) @ veff ----
    float invl[4];
#pragma unroll
    for (int r = 0; r < 4; ++r) invl[r] = 1.f / cx[8][r];
#pragma unroll
    for (int nb = 0; nb < 8; ++nb)
#pragma unroll
        for (int r = 0; r < 4; ++r)
            cx[nb][r] *= invl[r];
    __syncthreads();  // all waves done with kvN/kvT
#pragma unroll
    for (int nb = 0; nb < 8; ++nb)
#pragma unroll
        for (int r = 0; r < 4; ++r)
            ctxS[(w * 16 + g * 4 + r) * 136 + nb * 16 + m16] = __float2bfloat16(cx[nb][r]);
    {
        const bf16* vsrc = veffT_bf + (size_t)h * HSD * KVLD;
#pragma unroll
        for (int k = 0; k < 4; ++k) {
            int v = tid + k * 256;
            int row = v >> 4, cv = (v & 15) << 3;
            st8(vT + row * 136 + cv, ld8(vsrc + row * KVLD + cv));
        }
    }
    __syncthreads();

    f32x4 ya[4];
#pragma unroll
    for (int nb = 0; nb < 4; ++nb) ya[nb] = (f32x4){0.f, 0.f, 0.f, 0.f};
    short8 ca[4];
#pragma unroll
    for (int kf = 0; kf < 4; ++kf)
        ca[kf] = ld8(ctxS + (w * 16 + m16) * 136 + kf * 32 + g * 8);
#pragma unroll
    for (int nb = 0; nb < 4; ++nb)
#pragma unroll
        for (int kf = 0; kf < 4; ++kf) {
            short8 bv = ld8(vT + (nb * 16 + m16) * 136 + kf * 32 + g * 8);
            ya[nb] = __builtin_amdgcn_mfma_f32_16x16x32_bf16(ca[kf], bv, ya[nb], 0, 0, 0);
        }
#pragma unroll
    for (int nb = 0; nb < 4; ++nb)
#pragma unroll
        for (int r = 0; r < 4; ++r) {
            int rg = row0 + w * 16 + g * 4 + r;
            yout[((size_t)b * TD + rg) * CD + h * HSD + nb * 16 + m16] = ya[nb][r];
        }
}

extern "C" void kernel_launch(void* const* d_in, const int* in_sizes, int n_in,
                              void* d_out, int out_size, void* d_ws, size_t ws_size,
                              hipStream_t stream) {
    const float* x    = (const float*)d_in[0];
    const float* wdq  = (const float*)d_in[1];
    const float* wuq  = (const float*)d_in[2];
    const float* wdkv = (const float*)d_in[3];
    const float* wuk  = (const float*)d_in[4];
    const float* wuv  = (const float*)d_in[5];
    const float* wo   = (const float*)d_in[6];
    float* yout = (float*)d_out;                   // (B,T,C) fp32
    float* ckv_out = yout + (size_t)BD * TD * CD;  // (B,T,KVL) fp32

    // ws: ~5.0 MB
    float* ws = (float*)d_ws;
    float* M1   = ws;                                   // 16384 f
    float* M1P  = M1 + 16384;                           // 131072 f
    float* keff = M1P + 131072;                         // 131072 f
    bf16* Et_bf    = (bf16*)(keff + 131072);            // 262144 bf16 [h][l][i]
    bf16* veffT_bf = Et_bf + 262144;                    // 131072 bf16 [h*64+d][l]
    bf16* ckv_bf   = veffT_bf + 131072;                 // 524288 bf16 [b][t][l]
    bf16* ckvT_bf  = ckv_bf + 524288;                   // 524288 bf16 [b][l][t]
    bf16* Q1_bf    = ckvT_bf + 524288;                  // 524288 bf16 [b][t][i]

    dim3 m1grid(64, 8);
    k_m1p <<<m1grid, 256, 0, stream>>>(wuq, wuk, M1P);
    k_m1r <<<64,   256, 0, stream>>>(M1P, M1);
    k_keff<<<512,  256, 0, stream>>>(wdq, M1, keff);
    k_veff<<<512,  256, 0, stream>>>(wuv, wo, veffT_bf);
    k_E   <<<1024, 256, 0, stream>>>(wuq, keff, Et_bf);

    k_proj<<<TD * BD / 16, 256, 0, stream>>>(x, wdq, wdkv, Q1_bf, ckv_out, ckv_bf, ckvT_bf);

    dim3 grid(32, 32);
    k_flash<<<grid, 256, 0, stream>>>(Q1_bf, Et_bf, ckv_bf, ckvT_bf, veffT_bf, yout);
}

// Round 11
// 266.928 us; speedup vs baseline: 9.1027x; 1.0756x over previous
//
#include <hip/hip_runtime.h>
#include <hip/hip_bf16.h>

typedef __hip_bfloat16 bf16;
typedef __attribute__((ext_vector_type(8))) short short8;
typedef __attribute__((ext_vector_type(4))) float f32x4;

#define NHD 16
#define HSD 64
#define KVLD 128
#define QLD 128
#define CD 1024
#define BD 2
#define TD 2048

__device__ __forceinline__ short8 ld8(const bf16* p) { return *(const short8*)p; }
__device__ __forceinline__ void st8(bf16* p, short8 v) { *(short8*)p = v; }

__device__ __forceinline__ short8 cvt8(float4 a, float4 b) {
    union { short8 s; bf16 h[8]; } u;
    u.h[0] = __float2bfloat16(a.x); u.h[1] = __float2bfloat16(a.y);
    u.h[2] = __float2bfloat16(a.z); u.h[3] = __float2bfloat16(a.w);
    u.h[4] = __float2bfloat16(b.x); u.h[5] = __float2bfloat16(b.y);
    u.h[6] = __float2bfloat16(b.z); u.h[7] = __float2bfloat16(b.w);
    return u.s;
}
__device__ __forceinline__ void st4(bf16* p, float4 a) {
    union { short4 s; bf16 h[4]; } u;
    u.h[0] = __float2bfloat16(a.x); u.h[1] = __float2bfloat16(a.y);
    u.h[2] = __float2bfloat16(a.z); u.h[3] = __float2bfloat16(a.w);
    *(short4*)p = u.s;
}
__device__ __forceinline__ void st4f(bf16* p, f32x4 a) {
    union { short4 s; bf16 h[4]; } u;
    u.h[0] = __float2bfloat16(a[0]); u.h[1] = __float2bfloat16(a[1]);
    u.h[2] = __float2bfloat16(a[2]); u.h[3] = __float2bfloat16(a[3]);
    *(short4*)p = u.s;
}

// ---------- weight-chain precompute ----------

// M1 partials: K split 8 ways (grid (64,8))
__global__ __launch_bounds__(256) void k_m1p(const float* __restrict__ wuq,
                                             const float* __restrict__ wuk,
                                             float* __restrict__ m1p) {
    int idx = blockIdx.x * 256 + threadIdx.x;
    int i = idx >> 7, j = idx & 127;
    int c0 = blockIdx.y * 128;
    float acc = 0.f;
    for (int c = c0; c < c0 + 128; ++c)
        acc += wuq[c * QLD + i] * wuk[c * KVLD + j];
    m1p[blockIdx.y * 16384 + idx] = acc;
}

__global__ __launch_bounds__(256) void k_m1r(const float* __restrict__ m1p,
                                             float* __restrict__ m1) {
    int idx = blockIdx.x * 256 + threadIdx.x;
    float acc = 0.f;
#pragma unroll
    for (int p = 0; p < 8; ++p) acc += m1p[p * 16384 + idx];
    m1[idx] = acc;
}

__global__ __launch_bounds__(256) void k_keff(const float* __restrict__ wdq,
                                              const float* __restrict__ m1,
                                              float* __restrict__ keff) {
    int idx = blockIdx.x * 256 + threadIdx.x;
    int c = idx >> 7, j = idx & 127;
    float acc = 0.f;
    for (int i = 0; i < QLD; ++i)
        acc += wdq[i * CD + c] * m1[i * KVLD + j];
    keff[idx] = acc;
}

__global__ __launch_bounds__(256) void k_veff(const float* __restrict__ wuv,
                                              const float* __restrict__ wo,
                                              bf16* __restrict__ veffT_bf) {
    int idx = blockIdx.x * 256 + threadIdx.x;  // cc*128 + l
    int l = idx & 127;
    int cc = idx >> 7;
    float acc = 0.f;
    for (int c0 = 0; c0 < CD; ++c0)
        acc += wuv[c0 * KVLD + l] * wo[(size_t)cc * CD + c0];
    veffT_bf[idx] = __float2bfloat16(acc);
}

// Et scale = 0.125 * log2(e): softmax runs in exp2 domain
__global__ __launch_bounds__(256) void k_E(const float* __restrict__ wuq,
                                           const float* __restrict__ keff,
                                           bf16* __restrict__ Et_bf) {
    int idx = blockIdx.x * 256 + threadIdx.x;  // ((h*128+l)*128+i)
    int i = idx & 127;
    int l = (idx >> 7) & 127;
    int h = idx >> 14;
    float acc = 0.f;
    for (int d = 0; d < HSD; ++d)
        acc += wuq[(h * HSD + d) * QLD + i] * keff[(h * HSD + d) * KVLD + l];
    Et_bf[idx] = __float2bfloat16(0.1803368801f * acc);
}

// ---------- fused projection GEMM: [Q1 | ckv] = x @ [Wdq | Wdkv]^T ----------
// BM=16, BN=256, BK=64. Grid 256. Wave w handles cols [w*64, w*64+64).
__global__ __launch_bounds__(256) void k_proj(const float* __restrict__ x,
                                              const float* __restrict__ wdq,
                                              const float* __restrict__ wdkv,
                                              bf16* __restrict__ q1_bf,
                                              float* __restrict__ ckv_out,
                                              bf16* __restrict__ ckv_bf,
                                              bf16* __restrict__ ckvT_bf) {
    const int m0 = blockIdx.x * 16;
    const int tid = threadIdx.x;
    const int w = tid >> 6, lane = tid & 63, m16 = lane & 15, g = lane >> 4;

    __shared__ __align__(16) short As_raw[16 * 72];
    __shared__ __align__(16) short Bs_raw[256 * 72];
    bf16* As = (bf16*)As_raw;
    bf16* Bs = (bf16*)Bs_raw;

    f32x4 acc[4];
#pragma unroll
    for (int nb = 0; nb < 4; ++nb) acc[nb] = (f32x4){0.f, 0.f, 0.f, 0.f};

    for (int k0 = 0; k0 < CD; k0 += 64) {
        __syncthreads();
        {   // A: 16x64 tile of x
            int row = tid >> 4, kc = (tid & 15) << 2;
            float4 f = *(const float4*)(x + (size_t)(m0 + row) * CD + k0 + kc);
            st4(As + row * 72 + kc, f);
        }
#pragma unroll
        for (int kk = 0; kk < 8; ++kk) {  // B: 256x64 (rows 0-127 wdq, 128-255 wdkv)
            int v = tid + kk * 256;
            int row = v >> 3, kc = (v & 7) << 3;
            const float* wr = (row < 128) ? (wdq + (size_t)row * CD)
                                          : (wdkv + (size_t)(row - 128) * CD);
            const float* src = wr + k0 + kc;
            float4 f0 = *(const float4*)(src);
            float4 f1 = *(const float4*)(src + 4);
            st8(Bs + row * 72 + kc, cvt8(f0, f1));
        }
        __syncthreads();
        short8 aF[2];
#pragma unroll
        for (int kf = 0; kf < 2; ++kf)
            aF[kf] = ld8(As + m16 * 72 + kf * 32 + g * 8);
#pragma unroll
        for (int nb = 0; nb < 4; ++nb)
#pragma unroll
            for (int kf = 0; kf < 2; ++kf) {
                short8 bF = ld8(Bs + (w * 64 + nb * 16 + m16) * 72 + kf * 32 + g * 8);
                acc[nb] = __builtin_amdgcn_mfma_f32_16x16x32_bf16(aF[kf], bF, acc[nb], 0, 0, 0);
            }
    }

#pragma unroll
    for (int nb = 0; nb < 4; ++nb)
#pragma unroll
        for (int r = 0; r < 4; ++r) {
            int t = m0 + g * 4 + r;
            int col = w * 64 + nb * 16 + m16;
            float v = acc[nb][r];
            if (col < 128) {
                q1_bf[(size_t)t * QLD + col] = __float2bfloat16(v);
            } else {
                int l = col - 128;
                ckv_out[(size_t)t * KVLD + l] = v;
                bf16 hv = __float2bfloat16(v);
                ckv_bf[(size_t)t * KVLD + l] = hv;
                int b = t >> 11, tl = t & 2047;
                ckvT_bf[((size_t)b * KVLD + l) * TD + tl] = hv;
            }
        }
}

// ---------- MFMA flash attention, transposed-S formulation ----------
// Grid (32 hb, 32): qt = 31 - blockIdx.y (LPT).
// Sᵀ = kv·qlᵀ: C-layout lane holds ONE q (col=m16) but only a g-subset of its 64
// s-values (s_local = nb*16 + g*4 + r). Row max therefore needs a 2-shuffle reduce
// across the g-quartet (xor 16, 32) — NOT lane-local (round-10 bug: partial maxima
// diverged per g; fully-masked diag lanes gave exp2(-inf - -inf) = NaN).
// Pᵀ stored as pS[q][s]: b64 contiguous writes, ld8 reads.
// ctxᵀ = kvTᵀ·Pᵀ (9th n-block = ones rows -> denominator in every lane of cx[8]).
// yᵀ = veffT·ctxᵀ -> D[d][q] -> float4 y stores.
// LDS (shorts): [0,8704) kvN 64x136 | [8704,19072) kvT 144x72 (rows 128..143 ones)
//               [19072,23680) pS 4 x 16x72.  47360 B -> 3 blocks/CU.
__global__ __launch_bounds__(256, 3) void k_flash(const bf16* __restrict__ Q1_bf,
                                                  const bf16* __restrict__ Et_bf,
                                                  const bf16* __restrict__ ckv_bf,
                                                  const bf16* __restrict__ ckvT_bf,
                                                  const bf16* __restrict__ veffT_bf,
                                                  float* __restrict__ yout) {
    const int h = blockIdx.x & 15;
    const int b = blockIdx.x >> 4;
    const int qt = 31 - blockIdx.y;
    const int tid = threadIdx.x;
    const int w = tid >> 6;
    const int lane = tid & 63;
    const int m16 = lane & 15;
    const int g = lane >> 4;
    const int row0 = qt * 64;

    __shared__ __align__(16) short smem_raw[23680];
    bf16* smem = (bf16*)smem_raw;
    bf16* kvN = smem;             // 64 x 136
    bf16* kvT = smem + 8704;      // 144 x 72 (rows 128..143 = ones)
    bf16* pS  = smem + 19072 + w * 1152;  // per-wave 16 x 72, layout [q][s]
    bf16* qlS = smem + 8704;      // prologue alias (rows 0..63 of kvT region)
    bf16* ctxS = smem;            // epilogue alias: [q 64][l 136]
    bf16* vT   = smem + 8704;     // epilogue alias: 64 x 136

    // all-ones rows of kvT (l = 128..143), written once
    {
        const bf16 one = __float2bfloat16(1.0f);
        for (int i = tid; i < 16 * 72; i += 256)
            kvT[9216 + i] = one;
    }

    // ---- prologue: ql = Q1_tile @ E[h] (E B-frags from global), ql -> qlA regs ----
    {
        const bf16* q1src = Q1_bf + ((size_t)(b * TD + row0)) * QLD;
#pragma unroll
        for (int k = 0; k < 4; ++k) {
            int v = tid + k * 256;
            int row = v >> 4, cv = (v & 15) << 3;
            st8(kvN + row * 136 + cv, ld8(q1src + row * QLD + cv));
        }
    }
    __syncthreads();
    {
        short8 aq[4];
#pragma unroll
        for (int kf = 0; kf < 4; ++kf)
            aq[kf] = ld8(kvN + (w * 16 + m16) * 136 + kf * 32 + g * 8);
        const bf16* Eh = Et_bf + (size_t)h * QLD * KVLD;
        f32x4 qc[8];
#pragma unroll
        for (int nb = 0; nb < 8; ++nb) qc[nb] = (f32x4){0.f, 0.f, 0.f, 0.f};
#pragma unroll
        for (int nb = 0; nb < 8; ++nb)
#pragma unroll
            for (int kf = 0; kf < 4; ++kf) {
                short8 bq = ld8(Eh + (nb * 16 + m16) * QLD + kf * 32 + g * 8);
                qc[nb] = __builtin_amdgcn_mfma_f32_16x16x32_bf16(aq[kf], bq, qc[nb], 0, 0, 0);
            }
        // ql C-layout -> row-major qlS (disjoint from kvN), reload as frags
#pragma unroll
        for (int nb = 0; nb < 8; ++nb)
#pragma unroll
            for (int r = 0; r < 4; ++r)
                qlS[(w * 16 + g * 4 + r) * 136 + nb * 16 + m16] = __float2bfloat16(qc[nb][r]);
    }
    __syncthreads();
    short8 qlA[4];
#pragma unroll
    for (int kf = 0; kf < 4; ++kf)
        qlA[kf] = ld8(qlS + (w * 16 + m16) * 136 + kf * 32 + g * 8);

    // ---- main loop ----
    f32x4 cx[9];
#pragma unroll
    for (int nb = 0; nb < 9; ++nb) cx[nb] = (f32x4){0.f, 0.f, 0.f, 0.f};
    float mrow = -INFINITY;                 // this lane's q-row running max
    const int rg = row0 + w * 16 + m16;     // this lane's q row (global)

    const bf16* ckb = ckv_bf + (size_t)b * TD * KVLD;
    const bf16* ckTb = ckvT_bf + (size_t)b * KVLD * TD;

    int nrow[4], ncol[4], trow[4], tcol[4];
#pragma unroll
    for (int k = 0; k < 4; ++k) {
        int v = tid + k * 256;
        nrow[k] = v >> 4; ncol[k] = (v & 15) << 3;
        trow[k] = v >> 3; tcol[k] = (v & 7) << 3;
    }
    short8 pfN[4], pfT[4];
#pragma unroll
    for (int k = 0; k < 4; ++k) {   // prefetch tile 0
        pfN[k] = ld8(ckb + (size_t)nrow[k] * KVLD + ncol[k]);
        pfT[k] = ld8(ckTb + (size_t)trow[k] * TD + tcol[k]);
    }

    for (int tile = 0; tile <= qt; ++tile) {
        const int s0 = tile * 64;
        const bool diag = (tile == qt);
        __syncthreads();  // previous iter's LDS reads (and prologue qlA reads) done
#pragma unroll
        for (int k = 0; k < 4; ++k) {
            st8(kvN + nrow[k] * 136 + ncol[k], pfN[k]);
            st8(kvT + trow[k] * 72 + tcol[k], pfT[k]);
        }
        __syncthreads();
        if (tile < qt) {
            const int s1 = s0 + 64;
#pragma unroll
            for (int k = 0; k < 4; ++k) {
                pfN[k] = ld8(ckb + (size_t)(s1 + nrow[k]) * KVLD + ncol[k]);
                pfT[k] = ld8(ckTb + (size_t)trow[k] * TD + s1 + tcol[k]);
            }
        }

        // S^T = kv @ ql^T : lane holds q = rg (col), s = s0 + nb*16 + g*4 + r (rows)
        f32x4 sa[4];
#pragma unroll
        for (int nb = 0; nb < 4; ++nb) sa[nb] = (f32x4){0.f, 0.f, 0.f, 0.f};
#pragma unroll
        for (int nb = 0; nb < 4; ++nb)
#pragma unroll
            for (int kf = 0; kf < 4; ++kf) {
                short8 ak = ld8(kvN + (nb * 16 + m16) * 136 + kf * 32 + g * 8);
                sa[nb] = __builtin_amdgcn_mfma_f32_16x16x32_bf16(ak, qlA[kf], sa[nb], 0, 0, 0);
            }

        if (diag) {
#pragma unroll
            for (int nb = 0; nb < 4; ++nb)
#pragma unroll
                for (int r = 0; r < 4; ++r) {
                    int sg = s0 + nb * 16 + g * 4 + r;
                    if (sg > rg) sa[nb][r] = -INFINITY;
                }
        }

        // online softmax: in-lane partial max, then 2-shuffle reduce across the
        // g-quartet (lanes m16, m16+16, m16+32, m16+48 share the q row)
        float mloc = sa[0][0];
#pragma unroll
        for (int nb = 0; nb < 4; ++nb)
#pragma unroll
            for (int r = 0; r < 4; ++r) mloc = fmaxf(mloc, sa[nb][r]);
        mloc = fmaxf(mloc, __shfl_xor(mloc, 16));
        mloc = fmaxf(mloc, __shfl_xor(mloc, 32));   // now the true row max (finite)
        if (__any(mloc > mrow)) {
            float mt = fmaxf(mrow, mloc);
            float al = exp2f(mrow - mt);   // 1.0 for lanes that didn't grow
            mrow = mt;
#pragma unroll
            for (int nb = 0; nb < 9; ++nb)
#pragma unroll
                for (int r = 0; r < 4; ++r) cx[nb][r] *= al;
        }

        // P^T -> pS[q][s]: 4 contiguous bf16 per (nb): b64 writes
#pragma unroll
        for (int nb = 0; nb < 4; ++nb) {
            float4 p4;
            p4.x = exp2f(sa[nb][0] - mrow);
            p4.y = exp2f(sa[nb][1] - mrow);
            p4.z = exp2f(sa[nb][2] - mrow);
            p4.w = exp2f(sa[nb][3] - mrow);
            st4(pS + m16 * 72 + nb * 16 + g * 4, p4);
        }
        __builtin_amdgcn_wave_barrier();  // pS per-wave; keep ds order

        // ctx^T += kvT' @ P^T ; nb=8 (ones) accumulates denominator in every lane
        short8 pA[2];
#pragma unroll
        for (int kf = 0; kf < 2; ++kf)
            pA[kf] = ld8(pS + m16 * 72 + kf * 32 + g * 8);
#pragma unroll
        for (int nb = 0; nb < 9; ++nb)
#pragma unroll
            for (int kf = 0; kf < 2; ++kf) {
                short8 av = ld8(kvT + (nb * 16 + m16) * 72 + kf * 32 + g * 8);
                cx[nb] = __builtin_amdgcn_mfma_f32_16x16x32_bf16(av, pA[kf], cx[nb], 0, 0, 0);
            }
    }

    // ---- epilogue: y^T = veffT @ (ctx^T / l) ----
    float invl = 1.f / cx[8][0];    // all rows of cx[8] hold the denom for q=rg
#pragma unroll
    for (int nb = 0; nb < 8; ++nb)
#pragma unroll
        for (int r = 0; r < 4; ++r) cx[nb][r] *= invl;
    __syncthreads();  // all waves done with kvN/kvT
    // ctxS[q][l]: lane writes row w*16+m16, cols nb*16+g*4..+3 (b64)
#pragma unroll
    for (int nb = 0; nb < 8; ++nb)
        st4f(ctxS + (w * 16 + m16) * 136 + nb * 16 + g * 4, cx[nb]);
    {
        const bf16* vsrc = veffT_bf + (size_t)h * HSD * KVLD;
#pragma unroll
        for (int k = 0; k < 4; ++k) {
            int v = tid + k * 256;
            int row = v >> 4, cv = (v & 15) << 3;
            st8(vT + row * 136 + cv, ld8(vsrc + row * KVLD + cv));
        }
    }
    __syncthreads();

    short8 cB[4];
#pragma unroll
    for (int kf = 0; kf < 4; ++kf)
        cB[kf] = ld8(ctxS + (w * 16 + m16) * 136 + kf * 32 + g * 8);
    f32x4 ya[4];
#pragma unroll
    for (int nb = 0; nb < 4; ++nb) ya[nb] = (f32x4){0.f, 0.f, 0.f, 0.f};
#pragma unroll
    for (int nb = 0; nb < 4; ++nb)
#pragma unroll
        for (int kf = 0; kf < 4; ++kf) {
            short8 av = ld8(vT + (nb * 16 + m16) * 136 + kf * 32 + g * 8);
            ya[nb] = __builtin_amdgcn_mfma_f32_16x16x32_bf16(av, cB[kf], ya[nb], 0, 0, 0);
        }
    // D[row = d = nb*16+g*4+r][col = q = m16] -> contiguous d: float4 stores
    float* yo = yout + ((size_t)b * TD + rg) * CD + h * HSD;
#pragma unroll
    for (int nb = 0; nb < 4; ++nb)
        *(float4*)(yo + nb * 16 + g * 4) = *(float4*)&ya[nb];
}

extern "C" void kernel_launch(void* const* d_in, const int* in_sizes, int n_in,
                              void* d_out, int out_size, void* d_ws, size_t ws_size,
                              hipStream_t stream) {
    const float* x    = (const float*)d_in[0];
    const float* wdq  = (const float*)d_in[1];
    const float* wuq  = (const float*)d_in[2];
    const float* wdkv = (const float*)d_in[3];
    const float* wuk  = (const float*)d_in[4];
    const float* wuv  = (const float*)d_in[5];
    const float* wo   = (const float*)d_in[6];
    float* yout = (float*)d_out;                   // (B,T,C) fp32
    float* ckv_out = yout + (size_t)BD * TD * CD;  // (B,T,KVL) fp32

    // ws: ~5.0 MB
    float* ws = (float*)d_ws;
    float* M1   = ws;                                   // 16384 f
    float* M1P  = M1 + 16384;                           // 131072 f
    float* keff = M1P + 131072;                         // 131072 f
    bf16* Et_bf    = (bf16*)(keff + 131072);            // 262144 bf16 [h][l][i]
    bf16* veffT_bf = Et_bf + 262144;                    // 131072 bf16 [h*64+d][l]
    bf16* ckv_bf   = veffT_bf + 131072;                 // 524288 bf16 [b][t][l]
    bf16* ckvT_bf  = ckv_bf + 524288;                   // 524288 bf16 [b][l][t]
    bf16* Q1_bf    = ckvT_bf + 524288;                  // 524288 bf16 [b][t][i]

    dim3 m1grid(64, 8);
    k_m1p <<<m1grid, 256, 0, stream>>>(wuq, wuk, M1P);
    k_m1r <<<64,   256, 0, stream>>>(M1P, M1);
    k_keff<<<512,  256, 0, stream>>>(wdq, M1, keff);
    k_veff<<<512,  256, 0, stream>>>(wuv, wo, veffT_bf);
    k_E   <<<1024, 256, 0, stream>>>(wuq, keff, Et_bf);

    k_proj<<<TD * BD / 16, 256, 0, stream>>>(x, wdq, wdkv, Q1_bf, ckv_out, ckv_bf, ckvT_bf);

    dim3 grid(32, 32);
    k_flash<<<grid, 256, 0, stream>>>(Q1_bf, Et_bf, ckv_bf, ckvT_bf, veffT_bf, yout);
}

// Round 12
// 263.293 us; speedup vs baseline: 9.2284x; 1.0138x over previous
//
#include <hip/hip_runtime.h>
#include <hip/hip_bf16.h>

typedef __hip_bfloat16 bf16;
typedef __attribute__((ext_vector_type(8))) short short8;
typedef __attribute__((ext_vector_type(4))) float f32x4;

#define NHD 16
#define HSD 64
#define KVLD 128
#define QLD 128
#define CD 1024
#define BD 2
#define TD 2048

__device__ __forceinline__ short8 ld8(const bf16* p) { return *(const short8*)p; }
__device__ __forceinline__ void st8(bf16* p, short8 v) { *(short8*)p = v; }

__device__ __forceinline__ short8 cvt8(float4 a, float4 b) {
    union { short8 s; bf16 h[8]; } u;
    u.h[0] = __float2bfloat16(a.x); u.h[1] = __float2bfloat16(a.y);
    u.h[2] = __float2bfloat16(a.z); u.h[3] = __float2bfloat16(a.w);
    u.h[4] = __float2bfloat16(b.x); u.h[5] = __float2bfloat16(b.y);
    u.h[6] = __float2bfloat16(b.z); u.h[7] = __float2bfloat16(b.w);
    return u.s;
}
__device__ __forceinline__ void st4(bf16* p, float4 a) {
    union { short4 s; bf16 h[4]; } u;
    u.h[0] = __float2bfloat16(a.x); u.h[1] = __float2bfloat16(a.y);
    u.h[2] = __float2bfloat16(a.z); u.h[3] = __float2bfloat16(a.w);
    *(short4*)p = u.s;
}
__device__ __forceinline__ void st4f(bf16* p, f32x4 a) {
    union { short4 s; bf16 h[4]; } u;
    u.h[0] = __float2bfloat16(a[0]); u.h[1] = __float2bfloat16(a[1]);
    u.h[2] = __float2bfloat16(a[2]); u.h[3] = __float2bfloat16(a[3]);
    *(short4*)p = u.s;
}

// ---------- weight-chain precompute ----------

__global__ __launch_bounds__(256) void k_m1p(const float* __restrict__ wuq,
                                             const float* __restrict__ wuk,
                                             float* __restrict__ m1p) {
    int idx = blockIdx.x * 256 + threadIdx.x;
    int i = idx >> 7, j = idx & 127;
    int c0 = blockIdx.y * 128;
    float acc = 0.f;
    for (int c = c0; c < c0 + 128; ++c)
        acc += wuq[c * QLD + i] * wuk[c * KVLD + j];
    m1p[blockIdx.y * 16384 + idx] = acc;
}

__global__ __launch_bounds__(256) void k_m1r(const float* __restrict__ m1p,
                                             float* __restrict__ m1) {
    int idx = blockIdx.x * 256 + threadIdx.x;
    float acc = 0.f;
#pragma unroll
    for (int p = 0; p < 8; ++p) acc += m1p[p * 16384 + idx];
    m1[idx] = acc;
}

__global__ __launch_bounds__(256) void k_keff(const float* __restrict__ wdq,
                                              const float* __restrict__ m1,
                                              float* __restrict__ keff) {
    int idx = blockIdx.x * 256 + threadIdx.x;
    int c = idx >> 7, j = idx & 127;
    float acc = 0.f;
    for (int i = 0; i < QLD; ++i)
        acc += wdq[i * CD + c] * m1[i * KVLD + j];
    keff[idx] = acc;
}

__global__ __launch_bounds__(256) void k_veff(const float* __restrict__ wuv,
                                              const float* __restrict__ wo,
                                              bf16* __restrict__ veffT_bf) {
    int idx = blockIdx.x * 256 + threadIdx.x;  // cc*128 + l
    int l = idx & 127;
    int cc = idx >> 7;
    float acc = 0.f;
    for (int c0 = 0; c0 < CD; ++c0)
        acc += wuv[c0 * KVLD + l] * wo[(size_t)cc * CD + c0];
    veffT_bf[idx] = __float2bfloat16(acc);
}

// Et scale = 0.125 * log2(e): softmax runs in exp2 domain
__global__ __launch_bounds__(256) void k_E(const float* __restrict__ wuq,
                                           const float* __restrict__ keff,
                                           bf16* __restrict__ Et_bf) {
    int idx = blockIdx.x * 256 + threadIdx.x;  // ((h*128+l)*128+i)
    int i = idx & 127;
    int l = (idx >> 7) & 127;
    int h = idx >> 14;
    float acc = 0.f;
    for (int d = 0; d < HSD; ++d)
        acc += wuq[(h * HSD + d) * QLD + i] * keff[(h * HSD + d) * KVLD + l];
    Et_bf[idx] = __float2bfloat16(0.1803368801f * acc);
}

// ---------- fused projection GEMM: [Q1 | ckv] = x @ [Wdq | Wdkv]^T ----------
__global__ __launch_bounds__(256) void k_proj(const float* __restrict__ x,
                                              const float* __restrict__ wdq,
                                              const float* __restrict__ wdkv,
                                              bf16* __restrict__ q1_bf,
                                              float* __restrict__ ckv_out,
                                              bf16* __restrict__ ckv_bf,
                                              bf16* __restrict__ ckvT_bf) {
    const int m0 = blockIdx.x * 16;
    const int tid = threadIdx.x;
    const int w = tid >> 6, lane = tid & 63, m16 = lane & 15, g = lane >> 4;

    __shared__ __align__(16) short As_raw[16 * 72];
    __shared__ __align__(16) short Bs_raw[256 * 72];
    bf16* As = (bf16*)As_raw;
    bf16* Bs = (bf16*)Bs_raw;

    f32x4 acc[4];
#pragma unroll
    for (int nb = 0; nb < 4; ++nb) acc[nb] = (f32x4){0.f, 0.f, 0.f, 0.f};

    for (int k0 = 0; k0 < CD; k0 += 64) {
        __syncthreads();
        {   // A: 16x64 tile of x
            int row = tid >> 4, kc = (tid & 15) << 2;
            float4 f = *(const float4*)(x + (size_t)(m0 + row) * CD + k0 + kc);
            st4(As + row * 72 + kc, f);
        }
#pragma unroll
        for (int kk = 0; kk < 8; ++kk) {  // B: 256x64 (rows 0-127 wdq, 128-255 wdkv)
            int v = tid + kk * 256;
            int row = v >> 3, kc = (v & 7) << 3;
            const float* wr = (row < 128) ? (wdq + (size_t)row * CD)
                                          : (wdkv + (size_t)(row - 128) * CD);
            const float* src = wr + k0 + kc;
            float4 f0 = *(const float4*)(src);
            float4 f1 = *(const float4*)(src + 4);
            st8(Bs + row * 72 + kc, cvt8(f0, f1));
        }
        __syncthreads();
        short8 aF[2];
#pragma unroll
        for (int kf = 0; kf < 2; ++kf)
            aF[kf] = ld8(As + m16 * 72 + kf * 32 + g * 8);
#pragma unroll
        for (int nb = 0; nb < 4; ++nb)
#pragma unroll
            for (int kf = 0; kf < 2; ++kf) {
                short8 bF = ld8(Bs + (w * 64 + nb * 16 + m16) * 72 + kf * 32 + g * 8);
                acc[nb] = __builtin_amdgcn_mfma_f32_16x16x32_bf16(aF[kf], bF, acc[nb], 0, 0, 0);
            }
    }

#pragma unroll
    for (int nb = 0; nb < 4; ++nb)
#pragma unroll
        for (int r = 0; r < 4; ++r) {
            int t = m0 + g * 4 + r;
            int col = w * 64 + nb * 16 + m16;
            float v = acc[nb][r];
            if (col < 128) {
                q1_bf[(size_t)t * QLD + col] = __float2bfloat16(v);
            } else {
                int l = col - 128;
                ckv_out[(size_t)t * KVLD + l] = v;
                bf16 hv = __float2bfloat16(v);
                ckv_bf[(size_t)t * KVLD + l] = hv;
                int b = t >> 11, tl = t & 2047;
                ckvT_bf[((size_t)b * KVLD + l) * TD + tl] = hv;
            }
        }
}

// ---------- MFMA flash attention: paired q-tiles, 8-wave blocks ----------
// Grid (32 hb, 16 pairs), 512 threads. Waves 0-3 -> q-tile qhi=31-i, waves 4-7 ->
// q-tile qlo=i. One shared KV stream t=0..qhi; lo-waves skip compute for t>qlo.
// Block walls 17..32 tiles (max/avg 1.3 vs 2.0 unpaired) and 26% less staging.
// Per-wave math identical to round 11 (S^T = kv·ql^T, lane-per-q softmax with
// 2-shuffle quartet max, pS[q][s] b64 writes, PV via kvT with ones-rows denom).
// LDS (shorts): kvN 64x136 [0,8704) | kvT 144x72 [8704,19072) rows128-143=ones
//               pS 8 x 16x72 [19072,28288).  56576 B -> 2 blocks/CU, 16 waves/CU.
__global__ __launch_bounds__(512, 4) void k_flash(const bf16* __restrict__ Q1_bf,
                                                  const bf16* __restrict__ Et_bf,
                                                  const bf16* __restrict__ ckv_bf,
                                                  const bf16* __restrict__ ckvT_bf,
                                                  const bf16* __restrict__ veffT_bf,
                                                  float* __restrict__ yout) {
    const int h = blockIdx.x & 15;
    const int b = blockIdx.x >> 4;
    const int qlo = blockIdx.y;          // 0..15
    const int qhi = 31 - qlo;            // 16..31
    const int tid = threadIdx.x;         // 0..511
    const int w = tid >> 6;              // 0..7
    const int ws = w >> 2;               // 0 = hi set, 1 = lo set
    const int wq = w & 3;                // wave within set
    const int lane = tid & 63;
    const int m16 = lane & 15;
    const int g = lane >> 4;
    const int myqt = ws ? qlo : qhi;
    const int row0 = myqt * 64;

    __shared__ __align__(16) short smem_raw[28288];
    bf16* smem = (bf16*)smem_raw;
    bf16* kvN = smem;                    // 64 x 136
    bf16* kvT = smem + 8704;             // 144 x 72 (rows 128..143 = ones)
    bf16* pS  = smem + 19072 + w * 1152; // per-wave 16 x 72, [q][s]
    bf16* bufLo = kvT;                   // prologue alias: 64 x 136 (8704 sh)
    bf16* vT = smem + 19072;             // epilogue alias: 64 x 136 (in pS region)

    // all-ones rows of kvT (l = 128..143) — disjoint from bufLo (0..8704)
    {
        const bf16 one = __float2bfloat16(1.0f);
        for (int idx = tid; idx < 16 * 72; idx += 512)
            kvT[9216 + idx] = one;
    }

    // ---- prologue: ql = Q1_tile @ E[h] for both sets in parallel ----
    {
        const bf16* q1hi = Q1_bf + ((size_t)(b * TD + qhi * 64)) * QLD;
        const bf16* q1lo = Q1_bf + ((size_t)(b * TD + qlo * 64)) * QLD;
#pragma unroll
        for (int k = 0; k < 2; ++k) {
            int v = tid + k * 512;
            int row = v >> 4, cv = (v & 15) << 3;
            st8(kvN + row * 136 + cv, ld8(q1hi + row * QLD + cv));
            st8(bufLo + row * 136 + cv, ld8(q1lo + row * QLD + cv));
        }
    }
    __syncthreads();
    bf16* myQ1 = ws ? bufLo : kvN;
    {
        short8 aq[4];
#pragma unroll
        for (int kf = 0; kf < 4; ++kf)
            aq[kf] = ld8(myQ1 + (wq * 16 + m16) * 136 + kf * 32 + g * 8);
        const bf16* Eh = Et_bf + (size_t)h * QLD * KVLD;
        f32x4 qc[8];
#pragma unroll
        for (int nb = 0; nb < 8; ++nb) qc[nb] = (f32x4){0.f, 0.f, 0.f, 0.f};
#pragma unroll
        for (int nb = 0; nb < 8; ++nb)
#pragma unroll
            for (int kf = 0; kf < 4; ++kf) {
                short8 bq = ld8(Eh + (nb * 16 + m16) * QLD + kf * 32 + g * 8);
                qc[nb] = __builtin_amdgcn_mfma_f32_16x16x32_bf16(aq[kf], bq, qc[nb], 0, 0, 0);
            }
        __syncthreads();  // all waves done reading Q1 buffers
#pragma unroll
        for (int nb = 0; nb < 8; ++nb)
#pragma unroll
            for (int r = 0; r < 4; ++r)
                myQ1[(wq * 16 + g * 4 + r) * 136 + nb * 16 + m16] = __float2bfloat16(qc[nb][r]);
    }
    __syncthreads();
    short8 qlA[4];
#pragma unroll
    for (int kf = 0; kf < 4; ++kf)
        qlA[kf] = ld8(myQ1 + (wq * 16 + m16) * 136 + kf * 32 + g * 8);

    // ---- main loop ----
    f32x4 cx[9];
#pragma unroll
    for (int nb = 0; nb < 9; ++nb) cx[nb] = (f32x4){0.f, 0.f, 0.f, 0.f};
    float mrow = -INFINITY;
    const int rg = row0 + wq * 16 + m16;   // this lane's q row (global)

    const bf16* ckb = ckv_bf + (size_t)b * TD * KVLD;
    const bf16* ckTb = ckvT_bf + (size_t)b * KVLD * TD;

    int nrow[2], ncol[2], trow[2], tcol[2];
#pragma unroll
    for (int k = 0; k < 2; ++k) {
        int v = tid + k * 512;
        nrow[k] = v >> 4; ncol[k] = (v & 15) << 3;
        trow[k] = v >> 3; tcol[k] = (v & 7) << 3;
    }
    short8 pfN[2], pfT[2];
#pragma unroll
    for (int k = 0; k < 2; ++k) {   // prefetch tile 0
        pfN[k] = ld8(ckb + (size_t)nrow[k] * KVLD + ncol[k]);
        pfT[k] = ld8(ckTb + (size_t)trow[k] * TD + tcol[k]);
    }

    for (int tile = 0; tile <= qhi; ++tile) {
        const int s0 = tile * 64;
        __syncthreads();  // prior PV/pS reads + prologue qlA reads done
#pragma unroll
        for (int k = 0; k < 2; ++k) {
            st8(kvN + nrow[k] * 136 + ncol[k], pfN[k]);
            st8(kvT + trow[k] * 72 + tcol[k], pfT[k]);
        }
        __syncthreads();
        if (tile < qhi) {
            const int s1 = s0 + 64;
#pragma unroll
            for (int k = 0; k < 2; ++k) {
                pfN[k] = ld8(ckb + (size_t)(s1 + nrow[k]) * KVLD + ncol[k]);
                pfT[k] = ld8(ckTb + (size_t)trow[k] * TD + s1 + tcol[k]);
            }
        }

        if (ws == 0 || tile <= qlo) {   // wave-uniform: lo-set skips tiles > qlo
            // S^T = kv @ ql^T : lane holds q = rg, s = s0 + nb*16 + g*4 + r
            f32x4 sa[4];
#pragma unroll
            for (int nb = 0; nb < 4; ++nb) sa[nb] = (f32x4){0.f, 0.f, 0.f, 0.f};
#pragma unroll
            for (int nb = 0; nb < 4; ++nb)
#pragma unroll
                for (int kf = 0; kf < 4; ++kf) {
                    short8 ak = ld8(kvN + (nb * 16 + m16) * 136 + kf * 32 + g * 8);
                    sa[nb] = __builtin_amdgcn_mfma_f32_16x16x32_bf16(ak, qlA[kf], sa[nb], 0, 0, 0);
                }

            if (tile == myqt) {
#pragma unroll
                for (int nb = 0; nb < 4; ++nb)
#pragma unroll
                    for (int r = 0; r < 4; ++r) {
                        int sg = s0 + nb * 16 + g * 4 + r;
                        if (sg > rg) sa[nb][r] = -INFINITY;
                    }
            }

            // online softmax: lane partial max + 2-shuffle quartet reduce
            float mloc = sa[0][0];
#pragma unroll
            for (int nb = 0; nb < 4; ++nb)
#pragma unroll
                for (int r = 0; r < 4; ++r) mloc = fmaxf(mloc, sa[nb][r]);
            mloc = fmaxf(mloc, __shfl_xor(mloc, 16));
            mloc = fmaxf(mloc, __shfl_xor(mloc, 32));
            if (__any(mloc > mrow)) {
                float mt = fmaxf(mrow, mloc);
                float al = exp2f(mrow - mt);
                mrow = mt;
#pragma unroll
                for (int nb = 0; nb < 9; ++nb)
#pragma unroll
                    for (int r = 0; r < 4; ++r) cx[nb][r] *= al;
            }

            // P^T -> pS[q][s]: contiguous b64 writes
#pragma unroll
            for (int nb = 0; nb < 4; ++nb) {
                float4 p4;
                p4.x = exp2f(sa[nb][0] - mrow);
                p4.y = exp2f(sa[nb][1] - mrow);
                p4.z = exp2f(sa[nb][2] - mrow);
                p4.w = exp2f(sa[nb][3] - mrow);
                st4(pS + m16 * 72 + nb * 16 + g * 4, p4);
            }
            __builtin_amdgcn_wave_barrier();

            // ctx^T += kvT' @ P^T ; nb=8 (ones) accumulates denominator
            short8 pA[2];
#pragma unroll
            for (int kf = 0; kf < 2; ++kf)
                pA[kf] = ld8(pS + m16 * 72 + kf * 32 + g * 8);
#pragma unroll
            for (int nb = 0; nb < 9; ++nb)
#pragma unroll
                for (int kf = 0; kf < 2; ++kf) {
                    short8 av = ld8(kvT + (nb * 16 + m16) * 72 + kf * 32 + g * 8);
                    cx[nb] = __builtin_amdgcn_mfma_f32_16x16x32_bf16(av, pA[kf], cx[nb], 0, 0, 0);
                }
        }
    }

    // ---- epilogue: both sets concurrently, disjoint buffers ----
    float invl = 1.f / cx[8][0];
#pragma unroll
    for (int nb = 0; nb < 8; ++nb)
#pragma unroll
        for (int r = 0; r < 4; ++r) cx[nb][r] *= invl;
    __syncthreads();  // all waves done with kvN/kvT/pS
    bf16* ctxS = ws ? bufLo : kvN;   // 64 x 136 each
#pragma unroll
    for (int nb = 0; nb < 8; ++nb)
        st4f(ctxS + (wq * 16 + m16) * 136 + nb * 16 + g * 4, cx[nb]);
    {
        const bf16* vsrc = veffT_bf + (size_t)h * HSD * KVLD;
#pragma unroll
        for (int k = 0; k < 2; ++k) {
            int v = tid + k * 512;
            int row = v >> 4, cv = (v & 15) << 3;
            st8(vT + row * 136 + cv, ld8(vsrc + row * KVLD + cv));
        }
    }
    __syncthreads();

    short8 cB[4];
#pragma unroll
    for (int kf = 0; kf < 4; ++kf)
        cB[kf] = ld8(ctxS + (wq * 16 + m16) * 136 + kf * 32 + g * 8);
    f32x4 ya[4];
#pragma unroll
    for (int nb = 0; nb < 4; ++nb) ya[nb] = (f32x4){0.f, 0.f, 0.f, 0.f};
#pragma unroll
    for (int nb = 0; nb < 4; ++nb)
#pragma unroll
        for (int kf = 0; kf < 4; ++kf) {
            short8 av = ld8(vT + (nb * 16 + m16) * 136 + kf * 32 + g * 8);
            ya[nb] = __builtin_amdgcn_mfma_f32_16x16x32_bf16(av, cB[kf], ya[nb], 0, 0, 0);
        }
    float* yo = yout + ((size_t)b * TD + rg) * CD + h * HSD;
#pragma unroll
    for (int nb = 0; nb < 4; ++nb)
        *(float4*)(yo + nb * 16 + g * 4) = *(float4*)&ya[nb];
}

extern "C" void kernel_launch(void* const* d_in, const int* in_sizes, int n_in,
                              void* d_out, int out_size, void* d_ws, size_t ws_size,
                              hipStream_t stream) {
    const float* x    = (const float*)d_in[0];
    const float* wdq  = (const float*)d_in[1];
    const float* wuq  = (const float*)d_in[2];
    const float* wdkv = (const float*)d_in[3];
    const float* wuk  = (const float*)d_in[4];
    const float* wuv  = (const float*)d_in[5];
    const float* wo   = (const float*)d_in[6];
    float* yout = (float*)d_out;                   // (B,T,C) fp32
    float* ckv_out = yout + (size_t)BD * TD * CD;  // (B,T,KVL) fp32

    // ws: ~5.0 MB
    float* ws = (float*)d_ws;
    float* M1   = ws;                                   // 16384 f
    float* M1P  = M1 + 16384;                           // 131072 f
    float* keff = M1P + 131072;                         // 131072 f
    bf16* Et_bf    = (bf16*)(keff + 131072);            // 262144 bf16 [h][l][i]
    bf16* veffT_bf = Et_bf + 262144;                    // 131072 bf16 [h*64+d][l]
    bf16* ckv_bf   = veffT_bf + 131072;                 // 524288 bf16 [b][t][l]
    bf16* ckvT_bf  = ckv_bf + 524288;                   // 524288 bf16 [b][l][t]
    bf16* Q1_bf    = ckvT_bf + 524288;                  // 524288 bf16 [b][t][i]

    dim3 m1grid(64, 8);
    k_m1p <<<m1grid, 256, 0, stream>>>(wuq, wuk, M1P);
    k_m1r <<<64,   256, 0, stream>>>(M1P, M1);
    k_keff<<<512,  256, 0, stream>>>(wdq, M1, keff);
    k_veff<<<512,  256, 0, stream>>>(wuv, wo, veffT_bf);
    k_E   <<<1024, 256, 0, stream>>>(wuq, keff, Et_bf);

    k_proj<<<TD * BD / 16, 256, 0, stream>>>(x, wdq, wdkv, Q1_bf, ckv_out, ckv_bf, ckvT_bf);

    dim3 grid(32, 16);
    k_flash<<<grid, 512, 0, stream>>>(Q1_bf, Et_bf, ckv_bf, ckvT_bf, veffT_bf, yout);
}